// Round 1
// baseline (832.321 us; speedup 1.0000x reference)
//
#include <hip/hip_runtime.h>

#define NN 50000
#define IN_F 32
#define HID 64
#define N_LAYERS 3
#define BN_EPS 1e-5f

__global__ __launch_bounds__(256) void k_init_deg(float* deg, int n) {
    int i = blockIdx.x * blockDim.x + threadIdx.x;
    if (i < n) deg[i] = 1.0f;  // self-loop
}

__global__ __launch_bounds__(256) void k_deg_count(const int* __restrict__ dst, float* deg, int e) {
    int i = blockIdx.x * blockDim.x + threadIdx.x;
    if (i < e) atomicAdd(&deg[dst[i]], 1.0f);
}

__global__ __launch_bounds__(256) void k_dinv(float* deg, int n) {
    int i = blockIdx.x * blockDim.x + threadIdx.x;
    if (i < n) deg[i] = rsqrtf(fmaxf(deg[i], 1.0f));
}

// h = relu(x @ W_embed + b_embed)   [n,32]@[32,64]
__global__ __launch_bounds__(256) void k_embed(const float* __restrict__ x,
                                               const float* __restrict__ W,
                                               const float* __restrict__ b,
                                               float* __restrict__ h, int n) {
    __shared__ float sW[IN_F * HID];  // 8 KB
    for (int i = threadIdx.x; i < IN_F * HID; i += blockDim.x) sW[i] = W[i];
    __syncthreads();
    int gid = blockIdx.x * blockDim.x + threadIdx.x;
    int node = gid >> 6, f = gid & 63;
    if (node >= n) return;
    const float* xr = x + (size_t)node * IN_F;
    float acc = b[f];
#pragma unroll
    for (int k = 0; k < IN_F; ++k) acc = fmaf(xr[k], sW[k * HID + f], acc);
    h[(size_t)node * HID + f] = fmaxf(acc, 0.0f);
}

// t = h @ W + b   [n,64]@[64,64]
__global__ __launch_bounds__(256) void k_conv(const float* __restrict__ h,
                                              const float* __restrict__ W,
                                              const float* __restrict__ b,
                                              float* __restrict__ t, int n) {
    __shared__ float sW[HID * HID];  // 16 KB
    for (int i = threadIdx.x; i < HID * HID; i += blockDim.x) sW[i] = W[i];
    __syncthreads();
    int gid = blockIdx.x * blockDim.x + threadIdx.x;
    int node = gid >> 6, f = gid & 63;
    if (node >= n) return;
    const float* hr = h + (size_t)node * HID;
    float acc = b[f];
#pragma unroll
    for (int k = 0; k < HID; ++k) acc = fmaf(hr[k], sW[k * HID + f], acc);
    t[(size_t)node * HID + f] = acc;
}

// agg init with self-loop contribution: agg[i] = t[i] * dinv[i]^2
__global__ __launch_bounds__(256) void k_agg_init(const float* __restrict__ t,
                                                  const float* __restrict__ dinv,
                                                  float* __restrict__ agg, int n) {
    int gid = blockIdx.x * blockDim.x + threadIdx.x;
    int node = gid >> 6;
    if (node >= n) return;
    float dv = dinv[node];
    agg[gid] = t[gid] * dv * dv;
}

// one wave per edge; lane = feature
__global__ __launch_bounds__(256) void k_scatter(const int* __restrict__ src,
                                                 const int* __restrict__ dst,
                                                 const float* __restrict__ t,
                                                 const float* __restrict__ dinv,
                                                 float* __restrict__ agg, int e) {
    int gid = blockIdx.x * blockDim.x + threadIdx.x;
    int edge = gid >> 6, f = gid & 63;
    if (edge >= e) return;
    int s = src[edge], d = dst[edge];
    float nrm = dinv[s] * dinv[d];
    atomicAdd(&agg[(size_t)d * HID + f], t[(size_t)s * HID + f] * nrm);
}

__global__ __launch_bounds__(128) void k_zero_stats(float* stats) {
    stats[threadIdx.x] = 0.0f;  // 128 entries: sum[64], sumsq[64]
}

__global__ __launch_bounds__(256) void k_bn_stats(const float* __restrict__ agg,
                                                  float* __restrict__ stats, int n) {
    __shared__ float ssum[256], ssq[256];
    int f = threadIdx.x & 63;
    int sub = threadIdx.x >> 6;
    float s = 0.0f, q = 0.0f;
    for (int node = blockIdx.x * 4 + sub; node < n; node += gridDim.x * 4) {
        float v = agg[(size_t)node * HID + f];
        s += v;
        q = fmaf(v, v, q);
    }
    ssum[threadIdx.x] = s;
    ssq[threadIdx.x] = q;
    __syncthreads();
    if (threadIdx.x < 64) {
        s = ssum[threadIdx.x] + ssum[threadIdx.x + 64] + ssum[threadIdx.x + 128] + ssum[threadIdx.x + 192];
        q = ssq[threadIdx.x] + ssq[threadIdx.x + 64] + ssq[threadIdx.x + 128] + ssq[threadIdx.x + 192];
        atomicAdd(&stats[f], s);
        atomicAdd(&stats[64 + f], q);
    }
}

// h = relu((agg-mu)*rsqrt(var+eps)*gamma + beta) + h   (h == residual, in d_out)
__global__ __launch_bounds__(256) void k_bn_apply(const float* __restrict__ agg,
                                                  const float* __restrict__ stats,
                                                  const float* __restrict__ gamma,
                                                  const float* __restrict__ beta,
                                                  float* __restrict__ h, int n, float invN) {
    int gid = blockIdx.x * blockDim.x + threadIdx.x;
    int node = gid >> 6, f = gid & 63;
    if (node >= n) return;
    float mu = stats[f] * invN;
    float var = fmaxf(stats[64 + f] * invN - mu * mu, 0.0f);
    float bn = (agg[gid] - mu) * rsqrtf(var + BN_EPS) * gamma[f] + beta[f];
    h[gid] = fmaxf(bn, 0.0f) + h[gid];
}

extern "C" void kernel_launch(void* const* d_in, const int* in_sizes, int n_in,
                              void* d_out, int out_size, void* d_ws, size_t ws_size,
                              hipStream_t stream) {
    const float* x       = (const float*)d_in[0];
    const int*   ei      = (const int*)d_in[1];
    const float* W_embed = (const float*)d_in[2];
    const float* b_embed = (const float*)d_in[3];
    const float* W_convs = (const float*)d_in[4];
    const float* b_convs = (const float*)d_in[5];
    const float* gamma   = (const float*)d_in[6];
    const float* beta    = (const float*)d_in[7];
    float* h = (float*)d_out;

    const int n = in_sizes[0] / IN_F;   // 50000
    const int e = in_sizes[1] / 2;      // 800000
    const int* src = ei;
    const int* dst = ei + e;

    float* t     = (float*)d_ws;                 // n*HID
    float* agg   = t + (size_t)n * HID;          // n*HID
    float* dinv  = agg + (size_t)n * HID;        // n
    float* stats = dinv + n;                     // 128

    const int nodeBlocks = (n + 255) / 256;
    const int nfBlocks   = (n * HID + 255) / 256;       // 12500
    const int edgeBlocks = (e + 255) / 256;
    const int efBlocks   = (int)(((size_t)e * HID + 255) / 256);  // 200000

    // degree / normalization
    k_init_deg<<<nodeBlocks, 256, 0, stream>>>(dinv, n);
    k_deg_count<<<edgeBlocks, 256, 0, stream>>>(dst, dinv, e);
    k_dinv<<<nodeBlocks, 256, 0, stream>>>(dinv, n);

    // embed
    k_embed<<<nfBlocks, 256, 0, stream>>>(x, W_embed, b_embed, h, n);

    const float invN = 1.0f / (float)n;
    for (int l = 0; l < N_LAYERS; ++l) {
        const float* Wl = W_convs + (size_t)l * HID * HID;
        const float* bl = b_convs + (size_t)l * HID;
        k_conv<<<nfBlocks, 256, 0, stream>>>(h, Wl, bl, t, n);
        k_agg_init<<<nfBlocks, 256, 0, stream>>>(t, dinv, agg, n);
        k_scatter<<<efBlocks, 256, 0, stream>>>(src, dst, t, dinv, agg, e);
        k_zero_stats<<<1, 128, 0, stream>>>(stats);
        k_bn_stats<<<512, 256, 0, stream>>>(agg, stats, n);
        k_bn_apply<<<nfBlocks, 256, 0, stream>>>(agg, stats, gamma, beta, h, n, invN);
    }
}

// Round 2
// 586.410 us; speedup vs baseline: 1.4193x; 1.4193x over previous
//
#include <hip/hip_runtime.h>

#define IN_F 32
#define HID 64
#define N_LAYERS 3
#define BN_EPS 1e-5f

// ---------------- CSR build ----------------
__global__ __launch_bounds__(256) void k_zero(int* fillcur, int* cursor, int n) {
    int i = blockIdx.x * blockDim.x + threadIdx.x;
    if (i < n) fillcur[i] = 0;
    if (i == 0) *cursor = 0;
}

__global__ __launch_bounds__(256) void k_hist(const int* __restrict__ dst, int* cnt, int e) {
    int i = blockIdx.x * blockDim.x + threadIdx.x;
    if (i < e) atomicAdd(&cnt[dst[i]], 1);
}

// rowbeg[i] = segment start (via atomic cursor), fillcur[i] = rowbeg, dinv = rsqrt(deg+1)
__global__ __launch_bounds__(256) void k_assign(int* fillcur, int* rowbeg, float* dinv,
                                                int* cursor, int n) {
    int i = blockIdx.x * blockDim.x + threadIdx.x;
    if (i >= n) return;
    int c = fillcur[i];
    int beg = atomicAdd(cursor, c);
    rowbeg[i] = beg;
    fillcur[i] = beg;
    dinv[i] = rsqrtf((float)(c + 1));
}

// after this kernel, fillcur[i] == segment end
__global__ __launch_bounds__(256) void k_fill(const int* __restrict__ src, const int* __restrict__ dst,
                                              int* fillcur, int* __restrict__ csr_src, int e) {
    int i = blockIdx.x * blockDim.x + threadIdx.x;
    if (i >= e) return;
    int pos = atomicAdd(&fillcur[dst[i]], 1);
    csr_src[pos] = src[i];
}

// ---------------- dense ops ----------------
// h = relu(x @ W_embed + b)   [n,32]@[32,64]
__global__ __launch_bounds__(256) void k_embed(const float* __restrict__ x,
                                               const float* __restrict__ W,
                                               const float* __restrict__ b,
                                               float* __restrict__ h, int n) {
    __shared__ float sW[IN_F * HID];
    for (int i = threadIdx.x; i < IN_F * HID; i += blockDim.x) sW[i] = W[i];
    __syncthreads();
    int gid = blockIdx.x * blockDim.x + threadIdx.x;
    int node = gid >> 6, f = gid & 63;
    if (node >= n) return;
    const float* xr = x + (size_t)node * IN_F;
    float acc = b[f];
#pragma unroll
    for (int k = 0; k < IN_F; ++k) acc = fmaf(xr[k], sW[k * HID + f], acc);
    h[(size_t)node * HID + f] = fmaxf(acc, 0.0f);
}

// t2 = (h @ W + b) * dinv[node]; block 0 also zeroes stats for the next aggregate
__global__ __launch_bounds__(256) void k_conv(const float* __restrict__ h,
                                              const float* __restrict__ W,
                                              const float* __restrict__ b,
                                              const float* __restrict__ dinv,
                                              float* __restrict__ t2,
                                              float* __restrict__ stats, int n) {
    __shared__ float sW[HID * HID];
    for (int i = threadIdx.x; i < HID * HID; i += blockDim.x) sW[i] = W[i];
    if (blockIdx.x == 0 && threadIdx.x < 2 * HID) stats[threadIdx.x] = 0.0f;
    __syncthreads();
    int gid = blockIdx.x * blockDim.x + threadIdx.x;
    int node = gid >> 6, f = gid & 63;
    if (node >= n) return;
    const float* hr = h + (size_t)node * HID;
    float acc = b[f];
#pragma unroll
    for (int k = 0; k < HID; ++k) acc = fmaf(hr[k], sW[k * HID + f], acc);
    t2[gid] = acc * dinv[node];
}

// one wave per node (grid-stride over nodes); 16-lane groups process 4 edges in flight.
// agg[d] = dinv[d] * (t2[d] + sum_{s in N(d)} t2[s]);  fused BN-stat accumulation.
__global__ __launch_bounds__(256) void k_aggregate(const int* __restrict__ rowbeg,
                                                   const int* __restrict__ rowend,
                                                   const int* __restrict__ csr_src,
                                                   const float* __restrict__ t2,
                                                   const float* __restrict__ dinv,
                                                   float* __restrict__ agg,
                                                   float* __restrict__ stats, int n) {
    __shared__ float lsum[HID], lsq[HID];
    if (threadIdx.x < HID) { lsum[threadIdx.x] = 0.0f; lsq[threadIdx.x] = 0.0f; }
    __syncthreads();

    int lane = threadIdx.x & 63;
    int grp = lane >> 4, l16 = lane & 15;
    int wid0 = (blockIdx.x * blockDim.x + threadIdx.x) >> 6;
    int stride = (gridDim.x * blockDim.x) >> 6;

    float4 ssum = make_float4(0.f, 0.f, 0.f, 0.f);
    float4 ssq  = make_float4(0.f, 0.f, 0.f, 0.f);

    for (int wid = wid0; wid < n; wid += stride) {
        int beg = rowbeg[wid], end = rowend[wid];
        float4 acc = make_float4(0.f, 0.f, 0.f, 0.f);
        for (int j = beg + grp; j < end; j += 4) {
            int s = csr_src[j];
            float4 v = ((const float4*)(t2 + (size_t)s * HID))[l16];
            acc.x += v.x; acc.y += v.y; acc.z += v.z; acc.w += v.w;
        }
#pragma unroll
        for (int off = 16; off < 64; off <<= 1) {
            acc.x += __shfl_xor(acc.x, off, 64);
            acc.y += __shfl_xor(acc.y, off, 64);
            acc.z += __shfl_xor(acc.z, off, 64);
            acc.w += __shfl_xor(acc.w, off, 64);
        }
        if (grp == 0) {
            float dv = dinv[wid];
            float4 sv = ((const float4*)(t2 + (size_t)wid * HID))[l16];
            float4 r;
            r.x = (acc.x + sv.x) * dv;
            r.y = (acc.y + sv.y) * dv;
            r.z = (acc.z + sv.z) * dv;
            r.w = (acc.w + sv.w) * dv;
            ((float4*)(agg + (size_t)wid * HID))[l16] = r;
            ssum.x += r.x; ssum.y += r.y; ssum.z += r.z; ssum.w += r.w;
            ssq.x = fmaf(r.x, r.x, ssq.x); ssq.y = fmaf(r.y, r.y, ssq.y);
            ssq.z = fmaf(r.z, r.z, ssq.z); ssq.w = fmaf(r.w, r.w, ssq.w);
        }
    }
    if (grp == 0) {
        int f0 = l16 * 4;
        atomicAdd(&lsum[f0 + 0], ssum.x); atomicAdd(&lsq[f0 + 0], ssq.x);
        atomicAdd(&lsum[f0 + 1], ssum.y); atomicAdd(&lsq[f0 + 1], ssq.y);
        atomicAdd(&lsum[f0 + 2], ssum.z); atomicAdd(&lsq[f0 + 2], ssq.z);
        atomicAdd(&lsum[f0 + 3], ssum.w); atomicAdd(&lsq[f0 + 3], ssq.w);
    }
    __syncthreads();
    if (threadIdx.x < HID) {
        atomicAdd(&stats[threadIdx.x], lsum[threadIdx.x]);
        atomicAdd(&stats[HID + threadIdx.x], lsq[threadIdx.x]);
    }
}

// h = relu((agg-mu)*rsqrt(var+eps)*gamma + beta) + h
__global__ __launch_bounds__(256) void k_bn_apply(const float* __restrict__ agg,
                                                  const float* __restrict__ stats,
                                                  const float* __restrict__ gamma,
                                                  const float* __restrict__ beta,
                                                  float* __restrict__ h, int n, float invN) {
    int gid = blockIdx.x * blockDim.x + threadIdx.x;
    int node = gid >> 6, f = gid & 63;
    if (node >= n) return;
    float mu = stats[f] * invN;
    float var = fmaxf(stats[HID + f] * invN - mu * mu, 0.0f);
    float bn = (agg[gid] - mu) * rsqrtf(var + BN_EPS) * gamma[f] + beta[f];
    h[gid] = fmaxf(bn, 0.0f) + h[gid];
}

extern "C" void kernel_launch(void* const* d_in, const int* in_sizes, int n_in,
                              void* d_out, int out_size, void* d_ws, size_t ws_size,
                              hipStream_t stream) {
    const float* x       = (const float*)d_in[0];
    const int*   ei      = (const int*)d_in[1];
    const float* W_embed = (const float*)d_in[2];
    const float* b_embed = (const float*)d_in[3];
    const float* W_convs = (const float*)d_in[4];
    const float* b_convs = (const float*)d_in[5];
    const float* gamma   = (const float*)d_in[6];
    const float* beta    = (const float*)d_in[7];
    float* h = (float*)d_out;

    const int n = in_sizes[0] / IN_F;   // 50000
    const int e = in_sizes[1] / 2;      // 800000
    const int* src = ei;
    const int* dst = ei + e;

    float* t2    = (float*)d_ws;                      // n*HID f32
    float* agg   = t2 + (size_t)n * HID;              // n*HID f32
    float* dinv  = agg + (size_t)n * HID;             // n f32
    float* stats = dinv + n;                          // 128 f32
    int*   rowbeg  = (int*)(stats + 2 * HID);         // n
    int*   fillcur = rowbeg + n;                      // n
    int*   csr_src = fillcur + n;                     // e
    int*   cursor  = csr_src + e;                     // 1

    const int nodeBlocks = (n + 255) / 256;
    const int nfBlocks   = (n * HID + 255) / 256;
    const int edgeBlocks = (e + 255) / 256;
    const int aggBlocks  = 3125;   // 12500 waves, 4 nodes/wave

    // CSR build
    k_zero<<<nodeBlocks, 256, 0, stream>>>(fillcur, cursor, n);
    k_hist<<<edgeBlocks, 256, 0, stream>>>(dst, fillcur, e);
    k_assign<<<nodeBlocks, 256, 0, stream>>>(fillcur, rowbeg, dinv, cursor, n);
    k_fill<<<edgeBlocks, 256, 0, stream>>>(src, dst, fillcur, csr_src, e);
    // now: rowbeg = seg start, fillcur = seg end

    k_embed<<<nfBlocks, 256, 0, stream>>>(x, W_embed, b_embed, h, n);

    const float invN = 1.0f / (float)n;
    for (int l = 0; l < N_LAYERS; ++l) {
        const float* Wl = W_convs + (size_t)l * HID * HID;
        const float* bl = b_convs + (size_t)l * HID;
        k_conv<<<nfBlocks, 256, 0, stream>>>(h, Wl, bl, dinv, t2, stats, n);
        k_aggregate<<<aggBlocks, 256, 0, stream>>>(rowbeg, fillcur, csr_src, t2, dinv,
                                                   agg, stats, n);
        k_bn_apply<<<nfBlocks, 256, 0, stream>>>(agg, stats, gamma, beta, h, n, invN);
    }
}

// Round 3
// 533.628 us; speedup vs baseline: 1.5597x; 1.0989x over previous
//
#include <hip/hip_runtime.h>

#define IN_F 32
#define HID 64
#define N_LAYERS 3
#define BN_EPS 1e-5f

// ---------------- CSR build ----------------
__global__ __launch_bounds__(256) void k_zero(int* fillcur, int* cursor, float* statsAll, int n) {
    int i = blockIdx.x * blockDim.x + threadIdx.x;
    if (i < n) fillcur[i] = 0;
    if (i == 0) *cursor = 0;
    if (i < 2 * HID * N_LAYERS) statsAll[i] = 0.0f;
}

__global__ __launch_bounds__(256) void k_hist(const int* __restrict__ dst, int* cnt, int e) {
    int i = blockIdx.x * blockDim.x + threadIdx.x;
    if (i < e) atomicAdd(&cnt[dst[i]], 1);
}

__global__ __launch_bounds__(256) void k_assign(int* fillcur, int* rowbeg, float* dinv,
                                                int* cursor, int n) {
    int i = blockIdx.x * blockDim.x + threadIdx.x;
    if (i >= n) return;
    int c = fillcur[i];
    int beg = atomicAdd(cursor, c);
    rowbeg[i] = beg;
    fillcur[i] = beg;
    dinv[i] = rsqrtf((float)(c + 1));
}

__global__ __launch_bounds__(256) void k_fill(const int* __restrict__ src, const int* __restrict__ dst,
                                              int* fillcur, int* __restrict__ csr_src, int e) {
    int i = blockIdx.x * blockDim.x + threadIdx.x;
    if (i >= e) return;
    int pos = atomicAdd(&fillcur[dst[i]], 1);
    csr_src[pos] = src[i];
}

// ---------------- fused dense ops ----------------
// h = relu(x@We + be); t2 = (h@Wc0 + bc0) * dinv
__global__ __launch_bounds__(256) void k_embed_conv(const float* __restrict__ x,
                                                    const float* __restrict__ We,
                                                    const float* __restrict__ be,
                                                    const float* __restrict__ Wc,
                                                    const float* __restrict__ bc,
                                                    const float* __restrict__ dinv,
                                                    float* __restrict__ h,
                                                    float* __restrict__ t2, int n) {
    __shared__ float sWe[IN_F * HID];   // 8 KB
    __shared__ float sWc[HID * HID];    // 16 KB
    __shared__ float sh[4][HID];        // 1 KB
    for (int i = threadIdx.x; i < IN_F * HID; i += blockDim.x) sWe[i] = We[i];
    for (int i = threadIdx.x; i < HID * HID; i += blockDim.x) sWc[i] = Wc[i];
    __syncthreads();
    int gid = blockIdx.x * blockDim.x + threadIdx.x;
    int node = gid >> 6, f = gid & 63, local = threadIdx.x >> 6;
    if (node >= n) return;
    const float* xr = x + (size_t)node * IN_F;
    float acc = be[f];
#pragma unroll
    for (int k = 0; k < IN_F; ++k) acc = fmaf(xr[k], sWe[k * HID + f], acc);
    float hv = fmaxf(acc, 0.0f);
    h[gid] = hv;
    sh[local][f] = hv;
    __syncthreads();
    float acc2 = bc[f];
#pragma unroll
    for (int k4 = 0; k4 < HID / 4; ++k4) {
        float4 hv4 = ((const float4*)sh[local])[k4];
        acc2 = fmaf(hv4.x, sWc[(k4 * 4 + 0) * HID + f], acc2);
        acc2 = fmaf(hv4.y, sWc[(k4 * 4 + 1) * HID + f], acc2);
        acc2 = fmaf(hv4.z, sWc[(k4 * 4 + 2) * HID + f], acc2);
        acc2 = fmaf(hv4.w, sWc[(k4 * 4 + 3) * HID + f], acc2);
    }
    t2[gid] = acc2 * dinv[node];
}

// hnew = relu(bn(agg)) + h;  h = hnew;  t2 = (hnew@W + b) * dinv
__global__ __launch_bounds__(256) void k_bn_conv(const float* __restrict__ agg,
                                                 const float* __restrict__ stats,
                                                 const float* __restrict__ gamma,
                                                 const float* __restrict__ beta,
                                                 const float* __restrict__ W,
                                                 const float* __restrict__ b,
                                                 const float* __restrict__ dinv,
                                                 float* __restrict__ h,
                                                 float* __restrict__ t2, int n, float invN) {
    __shared__ float sW[HID * HID];     // 16 KB
    __shared__ float sh[4][HID];
    for (int i = threadIdx.x; i < HID * HID; i += blockDim.x) sW[i] = W[i];
    __syncthreads();
    int gid = blockIdx.x * blockDim.x + threadIdx.x;
    int node = gid >> 6, f = gid & 63, local = threadIdx.x >> 6;
    if (node >= n) return;
    float mu = stats[f] * invN;
    float var = fmaxf(stats[HID + f] * invN - mu * mu, 0.0f);
    float bnv = (agg[gid] - mu) * rsqrtf(var + BN_EPS) * gamma[f] + beta[f];
    float hv = fmaxf(bnv, 0.0f) + h[gid];
    h[gid] = hv;
    sh[local][f] = hv;
    __syncthreads();
    float acc = b[f];
#pragma unroll
    for (int k4 = 0; k4 < HID / 4; ++k4) {
        float4 hv4 = ((const float4*)sh[local])[k4];
        acc = fmaf(hv4.x, sW[(k4 * 4 + 0) * HID + f], acc);
        acc = fmaf(hv4.y, sW[(k4 * 4 + 1) * HID + f], acc);
        acc = fmaf(hv4.z, sW[(k4 * 4 + 2) * HID + f], acc);
        acc = fmaf(hv4.w, sW[(k4 * 4 + 3) * HID + f], acc);
    }
    t2[gid] = acc * dinv[node];
}

// one 16-lane group per node; 4-deep unrolled gather for MLP.
// agg[d] = dinv[d] * (t2[d] + sum_{s in N(d)} t2[s]); fused BN stats.
__global__ __launch_bounds__(256) void k_aggregate(const int* __restrict__ rowbeg,
                                                   const int* __restrict__ rowend,
                                                   const int* __restrict__ csr_src,
                                                   const float* __restrict__ t2,
                                                   const float* __restrict__ dinv,
                                                   float* __restrict__ agg,
                                                   float* __restrict__ stats, int n) {
    __shared__ float lsum[HID], lsq[HID];
    if (threadIdx.x < HID) { lsum[threadIdx.x] = 0.0f; lsq[threadIdx.x] = 0.0f; }
    __syncthreads();

    int l16 = threadIdx.x & 15;
    int g0 = (blockIdx.x * blockDim.x + threadIdx.x) >> 4;
    int ngroups = (gridDim.x * blockDim.x) >> 4;

    float4 ssum = make_float4(0.f, 0.f, 0.f, 0.f);
    float4 ssq  = make_float4(0.f, 0.f, 0.f, 0.f);

    for (int node = g0; node < n; node += ngroups) {
        int beg = rowbeg[node], end = rowend[node];
        float4 acc = ((const float4*)(t2 + (size_t)node * HID))[l16];  // self
        int j = beg;
        for (; j + 4 <= end; j += 4) {
            int s0 = csr_src[j + 0];
            int s1 = csr_src[j + 1];
            int s2 = csr_src[j + 2];
            int s3 = csr_src[j + 3];
            float4 v0 = ((const float4*)(t2 + (size_t)s0 * HID))[l16];
            float4 v1 = ((const float4*)(t2 + (size_t)s1 * HID))[l16];
            float4 v2 = ((const float4*)(t2 + (size_t)s2 * HID))[l16];
            float4 v3 = ((const float4*)(t2 + (size_t)s3 * HID))[l16];
            acc.x += v0.x + v1.x + v2.x + v3.x;
            acc.y += v0.y + v1.y + v2.y + v3.y;
            acc.z += v0.z + v1.z + v2.z + v3.z;
            acc.w += v0.w + v1.w + v2.w + v3.w;
        }
        for (; j < end; ++j) {
            int s = csr_src[j];
            float4 v = ((const float4*)(t2 + (size_t)s * HID))[l16];
            acc.x += v.x; acc.y += v.y; acc.z += v.z; acc.w += v.w;
        }
        float dv = dinv[node];
        float4 r;
        r.x = acc.x * dv; r.y = acc.y * dv; r.z = acc.z * dv; r.w = acc.w * dv;
        ((float4*)(agg + (size_t)node * HID))[l16] = r;
        ssum.x += r.x; ssum.y += r.y; ssum.z += r.z; ssum.w += r.w;
        ssq.x = fmaf(r.x, r.x, ssq.x); ssq.y = fmaf(r.y, r.y, ssq.y);
        ssq.z = fmaf(r.z, r.z, ssq.z); ssq.w = fmaf(r.w, r.w, ssq.w);
    }

    // reduce across the 4 groups of each wave, then LDS, then global
#pragma unroll
    for (int off = 16; off < 64; off <<= 1) {
        ssum.x += __shfl_xor(ssum.x, off, 64); ssq.x += __shfl_xor(ssq.x, off, 64);
        ssum.y += __shfl_xor(ssum.y, off, 64); ssq.y += __shfl_xor(ssq.y, off, 64);
        ssum.z += __shfl_xor(ssum.z, off, 64); ssq.z += __shfl_xor(ssq.z, off, 64);
        ssum.w += __shfl_xor(ssum.w, off, 64); ssq.w += __shfl_xor(ssq.w, off, 64);
    }
    if ((threadIdx.x & 63) < 16) {
        int f0 = l16 * 4;
        atomicAdd(&lsum[f0 + 0], ssum.x); atomicAdd(&lsq[f0 + 0], ssq.x);
        atomicAdd(&lsum[f0 + 1], ssum.y); atomicAdd(&lsq[f0 + 1], ssq.y);
        atomicAdd(&lsum[f0 + 2], ssum.z); atomicAdd(&lsq[f0 + 2], ssq.z);
        atomicAdd(&lsum[f0 + 3], ssum.w); atomicAdd(&lsq[f0 + 3], ssq.w);
    }
    __syncthreads();
    if (threadIdx.x < HID) {
        atomicAdd(&stats[threadIdx.x], lsum[threadIdx.x]);
        atomicAdd(&stats[HID + threadIdx.x], lsq[threadIdx.x]);
    }
}

// final: h = relu(bn(agg)) + h
__global__ __launch_bounds__(256) void k_bn_apply(const float* __restrict__ agg,
                                                  const float* __restrict__ stats,
                                                  const float* __restrict__ gamma,
                                                  const float* __restrict__ beta,
                                                  float* __restrict__ h, int n, float invN) {
    int gid = blockIdx.x * blockDim.x + threadIdx.x;
    int node = gid >> 6, f = gid & 63;
    if (node >= n) return;
    float mu = stats[f] * invN;
    float var = fmaxf(stats[HID + f] * invN - mu * mu, 0.0f);
    float bn = (agg[gid] - mu) * rsqrtf(var + BN_EPS) * gamma[f] + beta[f];
    h[gid] = fmaxf(bn, 0.0f) + h[gid];
}

extern "C" void kernel_launch(void* const* d_in, const int* in_sizes, int n_in,
                              void* d_out, int out_size, void* d_ws, size_t ws_size,
                              hipStream_t stream) {
    const float* x       = (const float*)d_in[0];
    const int*   ei      = (const int*)d_in[1];
    const float* W_embed = (const float*)d_in[2];
    const float* b_embed = (const float*)d_in[3];
    const float* W_convs = (const float*)d_in[4];
    const float* b_convs = (const float*)d_in[5];
    const float* gamma   = (const float*)d_in[6];
    const float* beta    = (const float*)d_in[7];
    float* h = (float*)d_out;

    const int n = in_sizes[0] / IN_F;   // 50000
    const int e = in_sizes[1] / 2;      // 800000
    const int* src = ei;
    const int* dst = ei + e;

    float* t2       = (float*)d_ws;                   // n*HID
    float* agg      = t2 + (size_t)n * HID;           // n*HID
    float* dinv     = agg + (size_t)n * HID;          // n
    float* statsAll = dinv + n;                       // 3 * 128
    int*   rowbeg   = (int*)(statsAll + 2 * HID * N_LAYERS);  // n
    int*   fillcur  = rowbeg + n;                     // n
    int*   csr_src  = fillcur + n;                    // e
    int*   cursor   = csr_src + e;                    // 1

    const int nodeBlocks = (n + 255) / 256;
    const int nfBlocks   = (n * HID + 255) / 256;     // 12500
    const int edgeBlocks = (e + 255) / 256;
    const int aggBlocks  = (n * 16 + 255) / 256;      // 3125, one 16-lane group per node

    k_zero<<<nodeBlocks, 256, 0, stream>>>(fillcur, cursor, statsAll, n);
    k_hist<<<edgeBlocks, 256, 0, stream>>>(dst, fillcur, e);
    k_assign<<<nodeBlocks, 256, 0, stream>>>(fillcur, rowbeg, dinv, cursor, n);
    k_fill<<<edgeBlocks, 256, 0, stream>>>(src, dst, fillcur, csr_src, e);

    const float invN = 1.0f / (float)n;
    const float* W0 = W_convs;
    const float* b0 = b_convs;

    k_embed_conv<<<nfBlocks, 256, 0, stream>>>(x, W_embed, b_embed, W0, b0, dinv, h, t2, n);

    for (int l = 0; l < N_LAYERS; ++l) {
        float* stats = statsAll + (size_t)l * 2 * HID;
        k_aggregate<<<aggBlocks, 256, 0, stream>>>(rowbeg, fillcur, csr_src, t2, dinv,
                                                   agg, stats, n);
        if (l < N_LAYERS - 1) {
            const float* Wl = W_convs + (size_t)(l + 1) * HID * HID;
            const float* bl = b_convs + (size_t)(l + 1) * HID;
            k_bn_conv<<<nfBlocks, 256, 0, stream>>>(agg, stats, gamma, beta, Wl, bl, dinv,
                                                    h, t2, n, invN);
        } else {
            k_bn_apply<<<nfBlocks, 256, 0, stream>>>(agg, stats, gamma, beta, h, n, invN);
        }
    }
}

// Round 4
// 422.928 us; speedup vs baseline: 1.9680x; 1.2617x over previous
//
#include <hip/hip_runtime.h>

#define IN_F 32
#define HID 64
#define N_LAYERS 3
#define BN_EPS 1e-5f

__device__ __forceinline__ unsigned short f2bf(float x) {
    unsigned u = __float_as_uint(x);
    u += 0x7fffu + ((u >> 16) & 1u);
    return (unsigned short)(u >> 16);
}
__device__ __forceinline__ float bflo(unsigned v) { return __uint_as_float(v << 16); }
__device__ __forceinline__ float bfhi(unsigned v) { return __uint_as_float(v & 0xffff0000u); }

// ---------------- CSR build ----------------
__global__ __launch_bounds__(256) void k_zero(int* fillcur, int* cursor, float* statsAll, int n) {
    int i = blockIdx.x * blockDim.x + threadIdx.x;
    if (i < n) fillcur[i] = 0;
    if (i == 0) *cursor = 0;
    if (i < 2 * HID * N_LAYERS) statsAll[i] = 0.0f;
}

__global__ __launch_bounds__(256) void k_hist(const int* __restrict__ dst, int* cnt, int e) {
    int i = blockIdx.x * blockDim.x + threadIdx.x;
    if (i < e) atomicAdd(&cnt[dst[i]], 1);
}

// segment assignment via intra-wave exclusive scan + ONE cursor atomic per wave
__global__ __launch_bounds__(256) void k_assign(int* fillcur, int* rowbeg, float* dinv,
                                                int* cursor, int n) {
    int i = blockIdx.x * blockDim.x + threadIdx.x;
    int lane = threadIdx.x & 63;
    int c = (i < n) ? fillcur[i] : 0;
    int s = c;
#pragma unroll
    for (int off = 1; off < 64; off <<= 1) {
        int t = __shfl_up(s, off, 64);
        if (lane >= off) s += t;
    }
    int total = __shfl(s, 63, 64);
    int base = 0;
    if (lane == 63) base = atomicAdd(cursor, total);
    base = __shfl(base, 63, 64);
    if (i < n) {
        int beg = base + s - c;   // exclusive scan position
        rowbeg[i] = beg;
        fillcur[i] = beg;
        dinv[i] = rsqrtf((float)(c + 1));
    }
}

__global__ __launch_bounds__(256) void k_fill(const int* __restrict__ src, const int* __restrict__ dst,
                                              int* fillcur, int* __restrict__ csr_src, int e) {
    int i = blockIdx.x * blockDim.x + threadIdx.x;
    if (i >= e) return;
    int pos = atomicAdd(&fillcur[dst[i]], 1);
    csr_src[pos] = src[i];
}

// ---------------- fused dense ops ----------------
// h = relu(x@We + be); t2b = bf16((h@Wc0 + bc0) * dinv)
__global__ __launch_bounds__(256) void k_embed_conv(const float* __restrict__ x,
                                                    const float* __restrict__ We,
                                                    const float* __restrict__ be,
                                                    const float* __restrict__ Wc,
                                                    const float* __restrict__ bc,
                                                    const float* __restrict__ dinv,
                                                    float* __restrict__ h,
                                                    unsigned short* __restrict__ t2b, int n) {
    __shared__ float sWe[IN_F * HID];
    __shared__ float sWc[HID * HID];
    __shared__ float sh[4][HID];
    for (int i = threadIdx.x; i < IN_F * HID; i += blockDim.x) sWe[i] = We[i];
    for (int i = threadIdx.x; i < HID * HID; i += blockDim.x) sWc[i] = Wc[i];
    __syncthreads();
    int gid = blockIdx.x * blockDim.x + threadIdx.x;
    int node = gid >> 6, f = gid & 63, local = threadIdx.x >> 6;
    if (node >= n) return;
    const float* xr = x + (size_t)node * IN_F;
    float acc = be[f];
#pragma unroll
    for (int k = 0; k < IN_F; ++k) acc = fmaf(xr[k], sWe[k * HID + f], acc);
    float hv = fmaxf(acc, 0.0f);
    h[gid] = hv;
    sh[local][f] = hv;
    __syncthreads();
    float acc2 = bc[f];
#pragma unroll
    for (int k4 = 0; k4 < HID / 4; ++k4) {
        float4 hv4 = ((const float4*)sh[local])[k4];
        acc2 = fmaf(hv4.x, sWc[(k4 * 4 + 0) * HID + f], acc2);
        acc2 = fmaf(hv4.y, sWc[(k4 * 4 + 1) * HID + f], acc2);
        acc2 = fmaf(hv4.z, sWc[(k4 * 4 + 2) * HID + f], acc2);
        acc2 = fmaf(hv4.w, sWc[(k4 * 4 + 3) * HID + f], acc2);
    }
    t2b[gid] = f2bf(acc2 * dinv[node]);
}

// hnew = relu(bn(agg)) + h;  h = hnew;  t2b = bf16((hnew@W + b) * dinv)
__global__ __launch_bounds__(256) void k_bn_conv(const float* __restrict__ agg,
                                                 const float* __restrict__ stats,
                                                 const float* __restrict__ gamma,
                                                 const float* __restrict__ beta,
                                                 const float* __restrict__ W,
                                                 const float* __restrict__ b,
                                                 const float* __restrict__ dinv,
                                                 float* __restrict__ h,
                                                 unsigned short* __restrict__ t2b, int n, float invN) {
    __shared__ float sW[HID * HID];
    __shared__ float sh[4][HID];
    for (int i = threadIdx.x; i < HID * HID; i += blockDim.x) sW[i] = W[i];
    __syncthreads();
    int gid = blockIdx.x * blockDim.x + threadIdx.x;
    int node = gid >> 6, f = gid & 63, local = threadIdx.x >> 6;
    if (node >= n) return;
    float mu = stats[f] * invN;
    float var = fmaxf(stats[HID + f] * invN - mu * mu, 0.0f);
    float bnv = (agg[gid] - mu) * rsqrtf(var + BN_EPS) * gamma[f] + beta[f];
    float hv = fmaxf(bnv, 0.0f) + h[gid];
    h[gid] = hv;
    sh[local][f] = hv;
    __syncthreads();
    float acc = b[f];
#pragma unroll
    for (int k4 = 0; k4 < HID / 4; ++k4) {
        float4 hv4 = ((const float4*)sh[local])[k4];
        acc = fmaf(hv4.x, sW[(k4 * 4 + 0) * HID + f], acc);
        acc = fmaf(hv4.y, sW[(k4 * 4 + 1) * HID + f], acc);
        acc = fmaf(hv4.z, sW[(k4 * 4 + 2) * HID + f], acc);
        acc = fmaf(hv4.w, sW[(k4 * 4 + 3) * HID + f], acc);
    }
    t2b[gid] = f2bf(acc * dinv[node]);
}

// one 16-lane group per node; bf16 rows (128 B); 4-deep unrolled gather.
__global__ __launch_bounds__(256) void k_aggregate(const int* __restrict__ rowbeg,
                                                   const int* __restrict__ rowend,
                                                   const int* __restrict__ csr_src,
                                                   const unsigned short* __restrict__ t2b,
                                                   const float* __restrict__ dinv,
                                                   float* __restrict__ agg,
                                                   float* __restrict__ stats, int n) {
    __shared__ float lsum[HID], lsq[HID];
    if (threadIdx.x < HID) { lsum[threadIdx.x] = 0.0f; lsq[threadIdx.x] = 0.0f; }
    __syncthreads();

    int l16 = threadIdx.x & 15;
    int g0 = (blockIdx.x * blockDim.x + threadIdx.x) >> 4;
    int ngroups = (gridDim.x * blockDim.x) >> 4;

    float4 ssum = make_float4(0.f, 0.f, 0.f, 0.f);
    float4 ssq  = make_float4(0.f, 0.f, 0.f, 0.f);

    for (int node = g0; node < n; node += ngroups) {
        int beg = rowbeg[node], end = rowend[node];
        uint2 sv = ((const uint2*)(t2b + (size_t)node * HID))[l16];
        float4 acc;
        acc.x = bflo(sv.x); acc.y = bfhi(sv.x);
        acc.z = bflo(sv.y); acc.w = bfhi(sv.y);
        int j = beg;
        for (; j + 4 <= end; j += 4) {
            int s0 = csr_src[j + 0];
            int s1 = csr_src[j + 1];
            int s2 = csr_src[j + 2];
            int s3 = csr_src[j + 3];
            uint2 v0 = ((const uint2*)(t2b + (size_t)s0 * HID))[l16];
            uint2 v1 = ((const uint2*)(t2b + (size_t)s1 * HID))[l16];
            uint2 v2 = ((const uint2*)(t2b + (size_t)s2 * HID))[l16];
            uint2 v3 = ((const uint2*)(t2b + (size_t)s3 * HID))[l16];
            acc.x += bflo(v0.x) + bflo(v1.x) + bflo(v2.x) + bflo(v3.x);
            acc.y += bfhi(v0.x) + bfhi(v1.x) + bfhi(v2.x) + bfhi(v3.x);
            acc.z += bflo(v0.y) + bflo(v1.y) + bflo(v2.y) + bflo(v3.y);
            acc.w += bfhi(v0.y) + bfhi(v1.y) + bfhi(v2.y) + bfhi(v3.y);
        }
        for (; j < end; ++j) {
            int s = csr_src[j];
            uint2 v = ((const uint2*)(t2b + (size_t)s * HID))[l16];
            acc.x += bflo(v.x); acc.y += bfhi(v.x);
            acc.z += bflo(v.y); acc.w += bfhi(v.y);
        }
        float dv = dinv[node];
        float4 r;
        r.x = acc.x * dv; r.y = acc.y * dv; r.z = acc.z * dv; r.w = acc.w * dv;
        ((float4*)(agg + (size_t)node * HID))[l16] = r;
        ssum.x += r.x; ssum.y += r.y; ssum.z += r.z; ssum.w += r.w;
        ssq.x = fmaf(r.x, r.x, ssq.x); ssq.y = fmaf(r.y, r.y, ssq.y);
        ssq.z = fmaf(r.z, r.z, ssq.z); ssq.w = fmaf(r.w, r.w, ssq.w);
    }

#pragma unroll
    for (int off = 16; off < 64; off <<= 1) {
        ssum.x += __shfl_xor(ssum.x, off, 64); ssq.x += __shfl_xor(ssq.x, off, 64);
        ssum.y += __shfl_xor(ssum.y, off, 64); ssq.y += __shfl_xor(ssq.y, off, 64);
        ssum.z += __shfl_xor(ssum.z, off, 64); ssq.z += __shfl_xor(ssq.z, off, 64);
        ssum.w += __shfl_xor(ssum.w, off, 64); ssq.w += __shfl_xor(ssq.w, off, 64);
    }
    if ((threadIdx.x & 63) < 16) {
        int f0 = l16 * 4;
        atomicAdd(&lsum[f0 + 0], ssum.x); atomicAdd(&lsq[f0 + 0], ssq.x);
        atomicAdd(&lsum[f0 + 1], ssum.y); atomicAdd(&lsq[f0 + 1], ssq.y);
        atomicAdd(&lsum[f0 + 2], ssum.z); atomicAdd(&lsq[f0 + 2], ssq.z);
        atomicAdd(&lsum[f0 + 3], ssum.w); atomicAdd(&lsq[f0 + 3], ssq.w);
    }
    __syncthreads();
    if (threadIdx.x < HID) {
        atomicAdd(&stats[threadIdx.x], lsum[threadIdx.x]);
        atomicAdd(&stats[HID + threadIdx.x], lsq[threadIdx.x]);
    }
}

// final: h = relu(bn(agg)) + h
__global__ __launch_bounds__(256) void k_bn_apply(const float* __restrict__ agg,
                                                  const float* __restrict__ stats,
                                                  const float* __restrict__ gamma,
                                                  const float* __restrict__ beta,
                                                  float* __restrict__ h, int n, float invN) {
    int gid = blockIdx.x * blockDim.x + threadIdx.x;
    int node = gid >> 6, f = gid & 63;
    if (node >= n) return;
    float mu = stats[f] * invN;
    float var = fmaxf(stats[HID + f] * invN - mu * mu, 0.0f);
    float bn = (agg[gid] - mu) * rsqrtf(var + BN_EPS) * gamma[f] + beta[f];
    h[gid] = fmaxf(bn, 0.0f) + h[gid];
}

extern "C" void kernel_launch(void* const* d_in, const int* in_sizes, int n_in,
                              void* d_out, int out_size, void* d_ws, size_t ws_size,
                              hipStream_t stream) {
    const float* x       = (const float*)d_in[0];
    const int*   ei      = (const int*)d_in[1];
    const float* W_embed = (const float*)d_in[2];
    const float* b_embed = (const float*)d_in[3];
    const float* W_convs = (const float*)d_in[4];
    const float* b_convs = (const float*)d_in[5];
    const float* gamma   = (const float*)d_in[6];
    const float* beta    = (const float*)d_in[7];
    float* h = (float*)d_out;

    const int n = in_sizes[0] / IN_F;   // 50000
    const int e = in_sizes[1] / 2;      // 800000
    const int* src = ei;
    const int* dst = ei + e;

    unsigned short* t2b = (unsigned short*)d_ws;            // n*HID bf16
    float* agg      = (float*)(t2b + (size_t)n * HID);      // n*HID f32
    float* dinv     = agg + (size_t)n * HID;                // n
    float* statsAll = dinv + n;                             // 3*128
    int*   rowbeg   = (int*)(statsAll + 2 * HID * N_LAYERS);
    int*   fillcur  = rowbeg + n;
    int*   csr_src  = fillcur + n;
    int*   cursor   = csr_src + e;

    const int nodeBlocks = (n + 255) / 256;
    const int nfBlocks   = (n * HID + 255) / 256;   // 12500
    const int edgeBlocks = (e + 255) / 256;
    const int aggBlocks  = 2048;                    // 8 blocks/CU, grid-stride over nodes

    k_zero<<<nodeBlocks, 256, 0, stream>>>(fillcur, cursor, statsAll, n);
    k_hist<<<edgeBlocks, 256, 0, stream>>>(dst, fillcur, e);
    k_assign<<<nodeBlocks, 256, 0, stream>>>(fillcur, rowbeg, dinv, cursor, n);
    k_fill<<<edgeBlocks, 256, 0, stream>>>(src, dst, fillcur, csr_src, e);

    const float invN = 1.0f / (float)n;

    k_embed_conv<<<nfBlocks, 256, 0, stream>>>(x, W_embed, b_embed, W_convs, b_convs,
                                               dinv, h, t2b, n);

    for (int l = 0; l < N_LAYERS; ++l) {
        float* stats = statsAll + (size_t)l * 2 * HID;
        k_aggregate<<<aggBlocks, 256, 0, stream>>>(rowbeg, fillcur, csr_src, t2b, dinv,
                                                   agg, stats, n);
        if (l < N_LAYERS - 1) {
            const float* Wl = W_convs + (size_t)(l + 1) * HID * HID;
            const float* bl = b_convs + (size_t)(l + 1) * HID;
            k_bn_conv<<<nfBlocks, 256, 0, stream>>>(agg, stats, gamma, beta, Wl, bl, dinv,
                                                    h, t2b, n, invN);
        } else {
            k_bn_apply<<<nfBlocks, 256, 0, stream>>>(agg, stats, gamma, beta, h, n, invN);
        }
    }
}

// Round 5
// 366.883 us; speedup vs baseline: 2.2686x; 1.1528x over previous
//
#include <hip/hip_runtime.h>

#define IN_F 32
#define HID 64
#define N_LAYERS 3
#define BN_EPS 1e-5f

__device__ __forceinline__ unsigned short f2bf(float x) {
    unsigned u = __float_as_uint(x);
    u += 0x7fffu + ((u >> 16) & 1u);
    return (unsigned short)(u >> 16);
}
__device__ __forceinline__ float bflo(unsigned v) { return __uint_as_float(v << 16); }
__device__ __forceinline__ float bfhi(unsigned v) { return __uint_as_float(v & 0xffff0000u); }

// ---------------- CSR build ----------------
__global__ __launch_bounds__(256) void k_zero(int* fillcur, int* cursor, float* statsAll, int n) {
    int i = blockIdx.x * blockDim.x + threadIdx.x;
    if (i < n) fillcur[i] = 0;
    if (i == 0) *cursor = 0;
    if (i < 2 * HID * N_LAYERS) statsAll[i] = 0.0f;
}

__global__ __launch_bounds__(256) void k_hist(const int* __restrict__ dst, int* cnt, int e) {
    int i = blockIdx.x * blockDim.x + threadIdx.x;
    if (i < e) atomicAdd(&cnt[dst[i]], 1);
}

// segment assignment via intra-wave exclusive scan + ONE cursor atomic per wave
__global__ __launch_bounds__(256) void k_assign(int* fillcur, int* rowbeg, float* dinv,
                                                int* cursor, int n) {
    int i = blockIdx.x * blockDim.x + threadIdx.x;
    int lane = threadIdx.x & 63;
    int c = (i < n) ? fillcur[i] : 0;
    int s = c;
#pragma unroll
    for (int off = 1; off < 64; off <<= 1) {
        int t = __shfl_up(s, off, 64);
        if (lane >= off) s += t;
    }
    int total = __shfl(s, 63, 64);
    int base = 0;
    if (lane == 63) base = atomicAdd(cursor, total);
    base = __shfl(base, 63, 64);
    if (i < n) {
        int beg = base + s - c;
        rowbeg[i] = beg;
        fillcur[i] = beg;
        dinv[i] = rsqrtf((float)(c + 1));
    }
}

__global__ __launch_bounds__(256) void k_fill(const int* __restrict__ src, const int* __restrict__ dst,
                                              int* fillcur, int* __restrict__ csr_src, int e) {
    int i = blockIdx.x * blockDim.x + threadIdx.x;
    if (i >= e) return;
    int pos = atomicAdd(&fillcur[dst[i]], 1);
    csr_src[pos] = src[i];
}

// ---------------- fused dense ops (weight-stationary, grid-stride) ----------------
// h = relu(x@We + be); t2b = bf16((h@Wc0 + bc0) * dinv). One wave per node, no inner barriers.
__global__ __launch_bounds__(256) void k_embed_conv(const float* __restrict__ x,
                                                    const float* __restrict__ We,
                                                    const float* __restrict__ be,
                                                    const float* __restrict__ Wc,
                                                    const float* __restrict__ bc,
                                                    const float* __restrict__ dinv,
                                                    float* __restrict__ h,
                                                    unsigned short* __restrict__ t2b, int n) {
    __shared__ float sWe[IN_F * HID];   // 8 KB
    __shared__ float sWc[HID * HID];    // 16 KB
    __shared__ float sh[4][HID];        // wave-private rows
    for (int i = threadIdx.x; i < IN_F * HID; i += blockDim.x) sWe[i] = We[i];
    for (int i = threadIdx.x; i < HID * HID; i += blockDim.x) sWc[i] = Wc[i];
    __syncthreads();
    int f = threadIdx.x & 63;
    int wv = threadIdx.x >> 6;
    float bef = be[f], bcf = bc[f];
    int w0 = blockIdx.x * 4 + wv;
    int nw = gridDim.x * 4;
    for (int node = w0; node < n; node += nw) {
        const float* xr = x + (size_t)node * IN_F;
        float acc = bef;
#pragma unroll
        for (int k = 0; k < IN_F; ++k) acc = fmaf(xr[k], sWe[k * HID + f], acc);
        float hv = fmaxf(acc, 0.0f);
        h[(size_t)node * HID + f] = hv;
        sh[wv][f] = hv;                       // wave-private: no barrier needed
        float acc2 = bcf;
#pragma unroll
        for (int k4 = 0; k4 < HID / 4; ++k4) {
            float4 hv4 = ((const float4*)sh[wv])[k4];
            acc2 = fmaf(hv4.x, sWc[(k4 * 4 + 0) * HID + f], acc2);
            acc2 = fmaf(hv4.y, sWc[(k4 * 4 + 1) * HID + f], acc2);
            acc2 = fmaf(hv4.z, sWc[(k4 * 4 + 2) * HID + f], acc2);
            acc2 = fmaf(hv4.w, sWc[(k4 * 4 + 3) * HID + f], acc2);
        }
        t2b[(size_t)node * HID + f] = f2bf(acc2 * dinv[node]);
    }
}

// hnew = relu(bn(agg)) + h; h = hnew; t2b = bf16((hnew@W + b) * dinv). Grid-stride.
__global__ __launch_bounds__(256) void k_bn_conv(const float* __restrict__ agg,
                                                 const float* __restrict__ stats,
                                                 const float* __restrict__ gamma,
                                                 const float* __restrict__ beta,
                                                 const float* __restrict__ W,
                                                 const float* __restrict__ b,
                                                 const float* __restrict__ dinv,
                                                 float* __restrict__ h,
                                                 unsigned short* __restrict__ t2b, int n, float invN) {
    __shared__ float sW[HID * HID];     // 16 KB
    __shared__ float sh[4][HID];
    for (int i = threadIdx.x; i < HID * HID; i += blockDim.x) sW[i] = W[i];
    __syncthreads();
    int f = threadIdx.x & 63;
    int wv = threadIdx.x >> 6;
    float mu = stats[f] * invN;
    float var = fmaxf(stats[HID + f] * invN - mu * mu, 0.0f);
    float scale = rsqrtf(var + BN_EPS) * gamma[f];
    float shift = beta[f];
    float bf = b[f];
    int w0 = blockIdx.x * 4 + wv;
    int nw = gridDim.x * 4;
    for (int node = w0; node < n; node += nw) {
        size_t gid = (size_t)node * HID + f;
        float bnv = (agg[gid] - mu) * scale + shift;
        float hv = fmaxf(bnv, 0.0f) + h[gid];
        h[gid] = hv;
        sh[wv][f] = hv;                       // wave-private
        float acc = bf;
#pragma unroll
        for (int k4 = 0; k4 < HID / 4; ++k4) {
            float4 hv4 = ((const float4*)sh[wv])[k4];
            acc = fmaf(hv4.x, sW[(k4 * 4 + 0) * HID + f], acc);
            acc = fmaf(hv4.y, sW[(k4 * 4 + 1) * HID + f], acc);
            acc = fmaf(hv4.z, sW[(k4 * 4 + 2) * HID + f], acc);
            acc = fmaf(hv4.w, sW[(k4 * 4 + 3) * HID + f], acc);
        }
        t2b[gid] = f2bf(acc * dinv[node]);
    }
}

// one 16-lane group per node; bf16 rows (128 B); 4-deep unrolled gather.
__global__ __launch_bounds__(256) void k_aggregate(const int* __restrict__ rowbeg,
                                                   const int* __restrict__ rowend,
                                                   const int* __restrict__ csr_src,
                                                   const unsigned short* __restrict__ t2b,
                                                   const float* __restrict__ dinv,
                                                   float* __restrict__ agg,
                                                   float* __restrict__ stats, int n) {
    __shared__ float lsum[HID], lsq[HID];
    if (threadIdx.x < HID) { lsum[threadIdx.x] = 0.0f; lsq[threadIdx.x] = 0.0f; }
    __syncthreads();

    int l16 = threadIdx.x & 15;
    int g0 = (blockIdx.x * blockDim.x + threadIdx.x) >> 4;
    int ngroups = (gridDim.x * blockDim.x) >> 4;

    float4 ssum = make_float4(0.f, 0.f, 0.f, 0.f);
    float4 ssq  = make_float4(0.f, 0.f, 0.f, 0.f);

    for (int node = g0; node < n; node += ngroups) {
        int beg = rowbeg[node], end = rowend[node];
        uint2 sv = ((const uint2*)(t2b + (size_t)node * HID))[l16];
        float4 acc;
        acc.x = bflo(sv.x); acc.y = bfhi(sv.x);
        acc.z = bflo(sv.y); acc.w = bfhi(sv.y);
        int j = beg;
        for (; j + 4 <= end; j += 4) {
            int s0 = csr_src[j + 0];
            int s1 = csr_src[j + 1];
            int s2 = csr_src[j + 2];
            int s3 = csr_src[j + 3];
            uint2 v0 = ((const uint2*)(t2b + (size_t)s0 * HID))[l16];
            uint2 v1 = ((const uint2*)(t2b + (size_t)s1 * HID))[l16];
            uint2 v2 = ((const uint2*)(t2b + (size_t)s2 * HID))[l16];
            uint2 v3 = ((const uint2*)(t2b + (size_t)s3 * HID))[l16];
            acc.x += bflo(v0.x) + bflo(v1.x) + bflo(v2.x) + bflo(v3.x);
            acc.y += bfhi(v0.x) + bfhi(v1.x) + bfhi(v2.x) + bfhi(v3.x);
            acc.z += bflo(v0.y) + bflo(v1.y) + bflo(v2.y) + bflo(v3.y);
            acc.w += bfhi(v0.y) + bfhi(v1.y) + bfhi(v2.y) + bfhi(v3.y);
        }
        for (; j < end; ++j) {
            int s = csr_src[j];
            uint2 v = ((const uint2*)(t2b + (size_t)s * HID))[l16];
            acc.x += bflo(v.x); acc.y += bfhi(v.x);
            acc.z += bflo(v.y); acc.w += bfhi(v.y);
        }
        float dv = dinv[node];
        float4 r;
        r.x = acc.x * dv; r.y = acc.y * dv; r.z = acc.z * dv; r.w = acc.w * dv;
        ((float4*)(agg + (size_t)node * HID))[l16] = r;
        ssum.x += r.x; ssum.y += r.y; ssum.z += r.z; ssum.w += r.w;
        ssq.x = fmaf(r.x, r.x, ssq.x); ssq.y = fmaf(r.y, r.y, ssq.y);
        ssq.z = fmaf(r.z, r.z, ssq.z); ssq.w = fmaf(r.w, r.w, ssq.w);
    }

#pragma unroll
    for (int off = 16; off < 64; off <<= 1) {
        ssum.x += __shfl_xor(ssum.x, off, 64); ssq.x += __shfl_xor(ssq.x, off, 64);
        ssum.y += __shfl_xor(ssum.y, off, 64); ssq.y += __shfl_xor(ssq.y, off, 64);
        ssum.z += __shfl_xor(ssum.z, off, 64); ssq.z += __shfl_xor(ssq.z, off, 64);
        ssum.w += __shfl_xor(ssum.w, off, 64); ssq.w += __shfl_xor(ssq.w, off, 64);
    }
    if ((threadIdx.x & 63) < 16) {
        int f0 = l16 * 4;
        atomicAdd(&lsum[f0 + 0], ssum.x); atomicAdd(&lsq[f0 + 0], ssq.x);
        atomicAdd(&lsum[f0 + 1], ssum.y); atomicAdd(&lsq[f0 + 1], ssq.y);
        atomicAdd(&lsum[f0 + 2], ssum.z); atomicAdd(&lsq[f0 + 2], ssq.z);
        atomicAdd(&lsum[f0 + 3], ssum.w); atomicAdd(&lsq[f0 + 3], ssq.w);
    }
    __syncthreads();
    if (threadIdx.x < HID) {
        atomicAdd(&stats[threadIdx.x], lsum[threadIdx.x]);
        atomicAdd(&stats[HID + threadIdx.x], lsq[threadIdx.x]);
    }
}

// final: h = relu(bn(agg)) + h
__global__ __launch_bounds__(256) void k_bn_apply(const float* __restrict__ agg,
                                                  const float* __restrict__ stats,
                                                  const float* __restrict__ gamma,
                                                  const float* __restrict__ beta,
                                                  float* __restrict__ h, int n, float invN) {
    int gid = blockIdx.x * blockDim.x + threadIdx.x;
    int node = gid >> 6, f = gid & 63;
    if (node >= n) return;
    float mu = stats[f] * invN;
    float var = fmaxf(stats[HID + f] * invN - mu * mu, 0.0f);
    float bn = (agg[gid] - mu) * rsqrtf(var + BN_EPS) * gamma[f] + beta[f];
    h[gid] = fmaxf(bn, 0.0f) + h[gid];
}

extern "C" void kernel_launch(void* const* d_in, const int* in_sizes, int n_in,
                              void* d_out, int out_size, void* d_ws, size_t ws_size,
                              hipStream_t stream) {
    const float* x       = (const float*)d_in[0];
    const int*   ei      = (const int*)d_in[1];
    const float* W_embed = (const float*)d_in[2];
    const float* b_embed = (const float*)d_in[3];
    const float* W_convs = (const float*)d_in[4];
    const float* b_convs = (const float*)d_in[5];
    const float* gamma   = (const float*)d_in[6];
    const float* beta    = (const float*)d_in[7];
    float* h = (float*)d_out;

    const int n = in_sizes[0] / IN_F;   // 50000
    const int e = in_sizes[1] / 2;      // 800000
    const int* src = ei;
    const int* dst = ei + e;

    unsigned short* t2b = (unsigned short*)d_ws;            // n*HID bf16
    float* agg      = (float*)(t2b + (size_t)n * HID);      // n*HID f32
    float* dinv     = agg + (size_t)n * HID;                // n
    float* statsAll = dinv + n;                             // 3*128
    int*   rowbeg   = (int*)(statsAll + 2 * HID * N_LAYERS);
    int*   fillcur  = rowbeg + n;
    int*   csr_src  = fillcur + n;
    int*   cursor   = csr_src + e;

    const int nodeBlocks  = (n + 255) / 256;
    const int nfBlocks    = (n * HID + 255) / 256;   // 12500
    const int edgeBlocks  = (e + 255) / 256;
    const int aggBlocks   = 2048;    // 8 blocks/CU, grid-stride over nodes
    const int embedBlocks = 1536;    // 6 blocks/CU (25.6 KB LDS), weight-stationary
    const int convBlocks  = 2048;    // 17.4 KB LDS -> 8 blocks/CU

    k_zero<<<nodeBlocks, 256, 0, stream>>>(fillcur, cursor, statsAll, n);
    k_hist<<<edgeBlocks, 256, 0, stream>>>(dst, fillcur, e);
    k_assign<<<nodeBlocks, 256, 0, stream>>>(fillcur, rowbeg, dinv, cursor, n);
    k_fill<<<edgeBlocks, 256, 0, stream>>>(src, dst, fillcur, csr_src, e);

    const float invN = 1.0f / (float)n;

    k_embed_conv<<<embedBlocks, 256, 0, stream>>>(x, W_embed, b_embed, W_convs, b_convs,
                                                  dinv, h, t2b, n);

    for (int l = 0; l < N_LAYERS; ++l) {
        float* stats = statsAll + (size_t)l * 2 * HID;
        k_aggregate<<<aggBlocks, 256, 0, stream>>>(rowbeg, fillcur, csr_src, t2b, dinv,
                                                   agg, stats, n);
        if (l < N_LAYERS - 1) {
            const float* Wl = W_convs + (size_t)(l + 1) * HID * HID;
            const float* bl = b_convs + (size_t)(l + 1) * HID;
            k_bn_conv<<<convBlocks, 256, 0, stream>>>(agg, stats, gamma, beta, Wl, bl, dinv,
                                                      h, t2b, n, invN);
        } else {
            k_bn_apply<<<nfBlocks, 256, 0, stream>>>(agg, stats, gamma, beta, h, n, invN);
        }
    }
}

// Round 6
// 345.376 us; speedup vs baseline: 2.4099x; 1.0623x over previous
//
#include <hip/hip_runtime.h>

#define IN_F 32
#define HID 64
#define N_LAYERS 3
#define BN_EPS 1e-5f

__device__ __forceinline__ unsigned short f2bf(float x) {
    unsigned u = __float_as_uint(x);
    u += 0x7fffu + ((u >> 16) & 1u);
    return (unsigned short)(u >> 16);
}
__device__ __forceinline__ float bflo(unsigned v) { return __uint_as_float(v << 16); }
__device__ __forceinline__ float bfhi(unsigned v) { return __uint_as_float(v & 0xffff0000u); }

// ---------------- CSR build ----------------
__global__ __launch_bounds__(256) void k_zero(int* fillcur, int* cursor, float* statsAll, int n) {
    int i = blockIdx.x * blockDim.x + threadIdx.x;
    if (i < n) fillcur[i] = 0;
    if (i == 0) *cursor = 0;
    if (i < 2 * HID * N_LAYERS) statsAll[i] = 0.0f;
}

__global__ __launch_bounds__(256) void k_hist(const int* __restrict__ dst, int* cnt, int e) {
    int i = blockIdx.x * blockDim.x + threadIdx.x;
    if (i < e) atomicAdd(&cnt[dst[i]], 1);
}

// segment assignment via intra-wave exclusive scan + ONE cursor atomic per wave
__global__ __launch_bounds__(256) void k_assign(int* fillcur, int* rowbeg, float* dinv,
                                                int* cursor, int n) {
    int i = blockIdx.x * blockDim.x + threadIdx.x;
    int lane = threadIdx.x & 63;
    int c = (i < n) ? fillcur[i] : 0;
    int s = c;
#pragma unroll
    for (int off = 1; off < 64; off <<= 1) {
        int t = __shfl_up(s, off, 64);
        if (lane >= off) s += t;
    }
    int total = __shfl(s, 63, 64);
    int base = 0;
    if (lane == 63) base = atomicAdd(cursor, total);
    base = __shfl(base, 63, 64);
    if (i < n) {
        int beg = base + s - c;
        rowbeg[i] = beg;
        fillcur[i] = beg;
        dinv[i] = rsqrtf((float)(c + 1));
    }
}

__global__ __launch_bounds__(256) void k_fill(const int* __restrict__ src, const int* __restrict__ dst,
                                              int* fillcur, int* __restrict__ csr_src, int e) {
    int i = blockIdx.x * blockDim.x + threadIdx.x;
    if (i >= e) return;
    int pos = atomicAdd(&fillcur[dst[i]], 1);
    csr_src[pos] = src[i];
}

// ---------------- fused dense ops (weight-stationary, grid-stride) ----------------
__global__ __launch_bounds__(256) void k_embed_conv(const float* __restrict__ x,
                                                    const float* __restrict__ We,
                                                    const float* __restrict__ be,
                                                    const float* __restrict__ Wc,
                                                    const float* __restrict__ bc,
                                                    const float* __restrict__ dinv,
                                                    float* __restrict__ h,
                                                    unsigned short* __restrict__ t2b, int n) {
    __shared__ float sWe[IN_F * HID];
    __shared__ float sWc[HID * HID];
    __shared__ float sh[4][HID];
    for (int i = threadIdx.x; i < IN_F * HID; i += blockDim.x) sWe[i] = We[i];
    for (int i = threadIdx.x; i < HID * HID; i += blockDim.x) sWc[i] = Wc[i];
    __syncthreads();
    int f = threadIdx.x & 63;
    int wv = threadIdx.x >> 6;
    float bef = be[f], bcf = bc[f];
    int w0 = blockIdx.x * 4 + wv;
    int nw = gridDim.x * 4;
    for (int node = w0; node < n; node += nw) {
        const float* xr = x + (size_t)node * IN_F;
        float acc = bef;
#pragma unroll
        for (int k = 0; k < IN_F; ++k) acc = fmaf(xr[k], sWe[k * HID + f], acc);
        float hv = fmaxf(acc, 0.0f);
        h[(size_t)node * HID + f] = hv;
        sh[wv][f] = hv;
        float acc2 = bcf;
#pragma unroll
        for (int k4 = 0; k4 < HID / 4; ++k4) {
            float4 hv4 = ((const float4*)sh[wv])[k4];
            acc2 = fmaf(hv4.x, sWc[(k4 * 4 + 0) * HID + f], acc2);
            acc2 = fmaf(hv4.y, sWc[(k4 * 4 + 1) * HID + f], acc2);
            acc2 = fmaf(hv4.z, sWc[(k4 * 4 + 2) * HID + f], acc2);
            acc2 = fmaf(hv4.w, sWc[(k4 * 4 + 3) * HID + f], acc2);
        }
        t2b[(size_t)node * HID + f] = f2bf(acc2 * dinv[node]);
    }
}

__global__ __launch_bounds__(256) void k_bn_conv(const float* __restrict__ agg,
                                                 const float* __restrict__ stats,
                                                 const float* __restrict__ gamma,
                                                 const float* __restrict__ beta,
                                                 const float* __restrict__ W,
                                                 const float* __restrict__ b,
                                                 const float* __restrict__ dinv,
                                                 float* __restrict__ h,
                                                 unsigned short* __restrict__ t2b, int n, float invN) {
    __shared__ float sW[HID * HID];
    __shared__ float sh[4][HID];
    for (int i = threadIdx.x; i < HID * HID; i += blockDim.x) sW[i] = W[i];
    __syncthreads();
    int f = threadIdx.x & 63;
    int wv = threadIdx.x >> 6;
    float mu = stats[f] * invN;
    float var = fmaxf(stats[HID + f] * invN - mu * mu, 0.0f);
    float scale = rsqrtf(var + BN_EPS) * gamma[f];
    float shift = beta[f];
    float bf = b[f];
    int w0 = blockIdx.x * 4 + wv;
    int nw = gridDim.x * 4;
    for (int node = w0; node < n; node += nw) {
        size_t gid = (size_t)node * HID + f;
        float bnv = (agg[gid] - mu) * scale + shift;
        float hv = fmaxf(bnv, 0.0f) + h[gid];
        h[gid] = hv;
        sh[wv][f] = hv;
        float acc = bf;
#pragma unroll
        for (int k4 = 0; k4 < HID / 4; ++k4) {
            float4 hv4 = ((const float4*)sh[wv])[k4];
            acc = fmaf(hv4.x, sW[(k4 * 4 + 0) * HID + f], acc);
            acc = fmaf(hv4.y, sW[(k4 * 4 + 1) * HID + f], acc);
            acc = fmaf(hv4.z, sW[(k4 * 4 + 2) * HID + f], acc);
            acc = fmaf(hv4.w, sW[(k4 * 4 + 3) * HID + f], acc);
        }
        t2b[gid] = f2bf(acc * dinv[node]);
    }
}

// one 8-lane group per node (uint4 = full 128-B row per gather); unroll-8 edge loop.
__global__ __launch_bounds__(256) void k_aggregate(const int* __restrict__ rowbeg,
                                                   const int* __restrict__ rowend,
                                                   const int* __restrict__ csr_src,
                                                   const unsigned short* __restrict__ t2b,
                                                   const float* __restrict__ dinv,
                                                   float* __restrict__ agg,
                                                   float* __restrict__ stats, int n) {
    __shared__ float lsum[HID], lsq[HID];
    if (threadIdx.x < HID) { lsum[threadIdx.x] = 0.0f; lsq[threadIdx.x] = 0.0f; }
    __syncthreads();

    int l8 = threadIdx.x & 7;
    int node = blockIdx.x * 32 + (threadIdx.x >> 3);

    float4 r0 = make_float4(0.f, 0.f, 0.f, 0.f);
    float4 r1 = make_float4(0.f, 0.f, 0.f, 0.f);

    if (node < n) {
        int beg = rowbeg[node], end = rowend[node];
        uint4 sv = ((const uint4*)(t2b + (size_t)node * HID))[l8];
        float4 a0, a1;
        a0.x = bflo(sv.x); a0.y = bfhi(sv.x); a0.z = bflo(sv.y); a0.w = bfhi(sv.y);
        a1.x = bflo(sv.z); a1.y = bfhi(sv.z); a1.z = bflo(sv.w); a1.w = bfhi(sv.w);
        int j = beg;
        for (; j + 8 <= end; j += 8) {
            int s0 = csr_src[j + 0], s1 = csr_src[j + 1];
            int s2 = csr_src[j + 2], s3 = csr_src[j + 3];
            int s4 = csr_src[j + 4], s5 = csr_src[j + 5];
            int s6 = csr_src[j + 6], s7 = csr_src[j + 7];
            uint4 v0 = ((const uint4*)(t2b + (size_t)s0 * HID))[l8];
            uint4 v1 = ((const uint4*)(t2b + (size_t)s1 * HID))[l8];
            uint4 v2 = ((const uint4*)(t2b + (size_t)s2 * HID))[l8];
            uint4 v3 = ((const uint4*)(t2b + (size_t)s3 * HID))[l8];
            uint4 v4 = ((const uint4*)(t2b + (size_t)s4 * HID))[l8];
            uint4 v5 = ((const uint4*)(t2b + (size_t)s5 * HID))[l8];
            uint4 v6 = ((const uint4*)(t2b + (size_t)s6 * HID))[l8];
            uint4 v7 = ((const uint4*)(t2b + (size_t)s7 * HID))[l8];
            a0.x += bflo(v0.x) + bflo(v1.x) + bflo(v2.x) + bflo(v3.x)
                  + bflo(v4.x) + bflo(v5.x) + bflo(v6.x) + bflo(v7.x);
            a0.y += bfhi(v0.x) + bfhi(v1.x) + bfhi(v2.x) + bfhi(v3.x)
                  + bfhi(v4.x) + bfhi(v5.x) + bfhi(v6.x) + bfhi(v7.x);
            a0.z += bflo(v0.y) + bflo(v1.y) + bflo(v2.y) + bflo(v3.y)
                  + bflo(v4.y) + bflo(v5.y) + bflo(v6.y) + bflo(v7.y);
            a0.w += bfhi(v0.y) + bfhi(v1.y) + bfhi(v2.y) + bfhi(v3.y)
                  + bfhi(v4.y) + bfhi(v5.y) + bfhi(v6.y) + bfhi(v7.y);
            a1.x += bflo(v0.z) + bflo(v1.z) + bflo(v2.z) + bflo(v3.z)
                  + bflo(v4.z) + bflo(v5.z) + bflo(v6.z) + bflo(v7.z);
            a1.y += bfhi(v0.z) + bfhi(v1.z) + bfhi(v2.z) + bfhi(v3.z)
                  + bfhi(v4.z) + bfhi(v5.z) + bfhi(v6.z) + bfhi(v7.z);
            a1.z += bflo(v0.w) + bflo(v1.w) + bflo(v2.w) + bflo(v3.w)
                  + bflo(v4.w) + bflo(v5.w) + bflo(v6.w) + bflo(v7.w);
            a1.w += bfhi(v0.w) + bfhi(v1.w) + bfhi(v2.w) + bfhi(v3.w)
                  + bfhi(v4.w) + bfhi(v5.w) + bfhi(v6.w) + bfhi(v7.w);
        }
        for (; j < end; ++j) {
            int s = csr_src[j];
            uint4 v = ((const uint4*)(t2b + (size_t)s * HID))[l8];
            a0.x += bflo(v.x); a0.y += bfhi(v.x); a0.z += bflo(v.y); a0.w += bfhi(v.y);
            a1.x += bflo(v.z); a1.y += bfhi(v.z); a1.z += bflo(v.w); a1.w += bfhi(v.w);
        }
        float dv = dinv[node];
        r0.x = a0.x * dv; r0.y = a0.y * dv; r0.z = a0.z * dv; r0.w = a0.w * dv;
        r1.x = a1.x * dv; r1.y = a1.y * dv; r1.z = a1.z * dv; r1.w = a1.w * dv;
        float4* ar = (float4*)(agg + (size_t)node * HID);
        ar[l8 * 2 + 0] = r0;
        ar[l8 * 2 + 1] = r1;
    }

    // BN stats: squares, then reduce across the 8 groups of the wave
    float4 q0, q1;
    q0.x = r0.x * r0.x; q0.y = r0.y * r0.y; q0.z = r0.z * r0.z; q0.w = r0.w * r0.w;
    q1.x = r1.x * r1.x; q1.y = r1.y * r1.y; q1.z = r1.z * r1.z; q1.w = r1.w * r1.w;
#pragma unroll
    for (int off = 8; off < 64; off <<= 1) {
        r0.x += __shfl_xor(r0.x, off, 64); q0.x += __shfl_xor(q0.x, off, 64);
        r0.y += __shfl_xor(r0.y, off, 64); q0.y += __shfl_xor(q0.y, off, 64);
        r0.z += __shfl_xor(r0.z, off, 64); q0.z += __shfl_xor(q0.z, off, 64);
        r0.w += __shfl_xor(r0.w, off, 64); q0.w += __shfl_xor(q0.w, off, 64);
        r1.x += __shfl_xor(r1.x, off, 64); q1.x += __shfl_xor(q1.x, off, 64);
        r1.y += __shfl_xor(r1.y, off, 64); q1.y += __shfl_xor(q1.y, off, 64);
        r1.z += __shfl_xor(r1.z, off, 64); q1.z += __shfl_xor(q1.z, off, 64);
        r1.w += __shfl_xor(r1.w, off, 64); q1.w += __shfl_xor(q1.w, off, 64);
    }
    if ((threadIdx.x & 63) < 8) {
        int f0 = l8 * 8;
        atomicAdd(&lsum[f0 + 0], r0.x); atomicAdd(&lsq[f0 + 0], q0.x);
        atomicAdd(&lsum[f0 + 1], r0.y); atomicAdd(&lsq[f0 + 1], q0.y);
        atomicAdd(&lsum[f0 + 2], r0.z); atomicAdd(&lsq[f0 + 2], q0.z);
        atomicAdd(&lsum[f0 + 3], r0.w); atomicAdd(&lsq[f0 + 3], q0.w);
        atomicAdd(&lsum[f0 + 4], r1.x); atomicAdd(&lsq[f0 + 4], q1.x);
        atomicAdd(&lsum[f0 + 5], r1.y); atomicAdd(&lsq[f0 + 5], q1.y);
        atomicAdd(&lsum[f0 + 6], r1.z); atomicAdd(&lsq[f0 + 6], q1.z);
        atomicAdd(&lsum[f0 + 7], r1.w); atomicAdd(&lsq[f0 + 7], q1.w);
    }
    __syncthreads();
    if (threadIdx.x < HID) {
        atomicAdd(&stats[threadIdx.x], lsum[threadIdx.x]);
        atomicAdd(&stats[HID + threadIdx.x], lsq[threadIdx.x]);
    }
}

// final: h = relu(bn(agg)) + h
__global__ __launch_bounds__(256) void k_bn_apply(const float* __restrict__ agg,
                                                  const float* __restrict__ stats,
                                                  const float* __restrict__ gamma,
                                                  const float* __restrict__ beta,
                                                  float* __restrict__ h, int n, float invN) {
    int gid = blockIdx.x * blockDim.x + threadIdx.x;
    int node = gid >> 6, f = gid & 63;
    if (node >= n) return;
    float mu = stats[f] * invN;
    float var = fmaxf(stats[HID + f] * invN - mu * mu, 0.0f);
    float bn = (agg[gid] - mu) * rsqrtf(var + BN_EPS) * gamma[f] + beta[f];
    h[gid] = fmaxf(bn, 0.0f) + h[gid];
}

extern "C" void kernel_launch(void* const* d_in, const int* in_sizes, int n_in,
                              void* d_out, int out_size, void* d_ws, size_t ws_size,
                              hipStream_t stream) {
    const float* x       = (const float*)d_in[0];
    const int*   ei      = (const int*)d_in[1];
    const float* W_embed = (const float*)d_in[2];
    const float* b_embed = (const float*)d_in[3];
    const float* W_convs = (const float*)d_in[4];
    const float* b_convs = (const float*)d_in[5];
    const float* gamma   = (const float*)d_in[6];
    const float* beta    = (const float*)d_in[7];
    float* h = (float*)d_out;

    const int n = in_sizes[0] / IN_F;   // 50000
    const int e = in_sizes[1] / 2;      // 800000
    const int* src = ei;
    const int* dst = ei + e;

    unsigned short* t2b = (unsigned short*)d_ws;            // n*HID bf16
    float* agg      = (float*)(t2b + (size_t)n * HID);      // n*HID f32
    float* dinv     = agg + (size_t)n * HID;                // n
    float* statsAll = dinv + n;                             // 3*128
    int*   rowbeg   = (int*)(statsAll + 2 * HID * N_LAYERS);
    int*   fillcur  = rowbeg + n;
    int*   csr_src  = fillcur + n;
    int*   cursor   = csr_src + e;

    const int nodeBlocks  = (n + 255) / 256;
    const int nfBlocks    = (n * HID + 255) / 256;
    const int edgeBlocks  = (e + 255) / 256;
    const int aggBlocks   = (n + 31) / 32;   // one 8-lane group per node
    const int embedBlocks = 1536;
    const int convBlocks  = 2048;

    k_zero<<<nodeBlocks, 256, 0, stream>>>(fillcur, cursor, statsAll, n);
    k_hist<<<edgeBlocks, 256, 0, stream>>>(dst, fillcur, e);
    k_assign<<<nodeBlocks, 256, 0, stream>>>(fillcur, rowbeg, dinv, cursor, n);
    k_fill<<<edgeBlocks, 256, 0, stream>>>(src, dst, fillcur, csr_src, e);

    const float invN = 1.0f / (float)n;

    k_embed_conv<<<embedBlocks, 256, 0, stream>>>(x, W_embed, b_embed, W_convs, b_convs,
                                                  dinv, h, t2b, n);

    for (int l = 0; l < N_LAYERS; ++l) {
        float* stats = statsAll + (size_t)l * 2 * HID;
        k_aggregate<<<aggBlocks, 256, 0, stream>>>(rowbeg, fillcur, csr_src, t2b, dinv,
                                                   agg, stats, n);
        if (l < N_LAYERS - 1) {
            const float* Wl = W_convs + (size_t)(l + 1) * HID * HID;
            const float* bl = b_convs + (size_t)(l + 1) * HID;
            k_bn_conv<<<convBlocks, 256, 0, stream>>>(agg, stats, gamma, beta, Wl, bl, dinv,
                                                      h, t2b, n, invN);
        } else {
            k_bn_apply<<<nfBlocks, 256, 0, stream>>>(agg, stats, gamma, beta, h, n, invN);
        }
    }
}

// Round 7
// 296.574 us; speedup vs baseline: 2.8065x; 1.1646x over previous
//
#include <hip/hip_runtime.h>

#define IN_F 32
#define HID 64
#define N_LAYERS 3
#define BN_EPS 1e-5f

__device__ __forceinline__ unsigned short f2bf(float x) {
    unsigned u = __float_as_uint(x);
    u += 0x7fffu + ((u >> 16) & 1u);
    return (unsigned short)(u >> 16);
}
__device__ __forceinline__ float bflo(unsigned v) { return __uint_as_float(v << 16); }
__device__ __forceinline__ float bfhi(unsigned v) { return __uint_as_float(v & 0xffff0000u); }

// ---------------- CSR build ----------------
__global__ __launch_bounds__(256) void k_zero(int* fillcur, int* cursor, float* statsAll, int n) {
    int i = blockIdx.x * blockDim.x + threadIdx.x;
    if (i < n) fillcur[i] = 0;
    if (i == 0) *cursor = 0;
    if (i < 2 * HID * N_LAYERS) statsAll[i] = 0.0f;
}

__global__ __launch_bounds__(256) void k_hist(const int* __restrict__ dst, int* cnt, int e) {
    int i = blockIdx.x * blockDim.x + threadIdx.x;
    if (i < e) atomicAdd(&cnt[dst[i]], 1);
}

__global__ __launch_bounds__(256) void k_assign(int* fillcur, int* rowbeg, float* dinv,
                                                int* cursor, int n) {
    int i = blockIdx.x * blockDim.x + threadIdx.x;
    int lane = threadIdx.x & 63;
    int c = (i < n) ? fillcur[i] : 0;
    int s = c;
#pragma unroll
    for (int off = 1; off < 64; off <<= 1) {
        int t = __shfl_up(s, off, 64);
        if (lane >= off) s += t;
    }
    int total = __shfl(s, 63, 64);
    int base = 0;
    if (lane == 63) base = atomicAdd(cursor, total);
    base = __shfl(base, 63, 64);
    if (i < n) {
        int beg = base + s - c;
        rowbeg[i] = beg;
        fillcur[i] = beg;
        dinv[i] = rsqrtf((float)(c + 1));
    }
}

__global__ __launch_bounds__(256) void k_fill(const int* __restrict__ src, const int* __restrict__ dst,
                                              int* fillcur, int* __restrict__ csr_src, int e) {
    int i = blockIdx.x * blockDim.x + threadIdx.x;
    if (i >= e) return;
    int pos = atomicAdd(&fillcur[dst[i]], 1);
    csr_src[pos] = src[i];
}

// ---------------- fused dense ops (weight-stationary, grid-stride) ----------------
// planar t2b: plane p (p=0,1) holds features p*32..p*32+31, 32 bf16 (64 B) per node.
__global__ __launch_bounds__(256) void k_embed_conv(const float* __restrict__ x,
                                                    const float* __restrict__ We,
                                                    const float* __restrict__ be,
                                                    const float* __restrict__ Wc,
                                                    const float* __restrict__ bc,
                                                    const float* __restrict__ dinv,
                                                    float* __restrict__ h,
                                                    unsigned short* __restrict__ t2b, int n) {
    __shared__ float sWe[IN_F * HID];
    __shared__ float sWc[HID * HID];
    __shared__ float sh[4][HID];
    for (int i = threadIdx.x; i < IN_F * HID; i += blockDim.x) sWe[i] = We[i];
    for (int i = threadIdx.x; i < HID * HID; i += blockDim.x) sWc[i] = Wc[i];
    __syncthreads();
    int f = threadIdx.x & 63;
    int wv = threadIdx.x >> 6;
    int plane = f >> 5, fin = f & 31;
    float bef = be[f], bcf = bc[f];
    int w0 = blockIdx.x * 4 + wv;
    int nw = gridDim.x * 4;
    for (int node = w0; node < n; node += nw) {
        const float* xr = x + (size_t)node * IN_F;
        float acc = bef;
#pragma unroll
        for (int k = 0; k < IN_F; ++k) acc = fmaf(xr[k], sWe[k * HID + f], acc);
        float hv = fmaxf(acc, 0.0f);
        h[(size_t)node * HID + f] = hv;
        sh[wv][f] = hv;
        float acc2 = bcf;
#pragma unroll
        for (int k4 = 0; k4 < HID / 4; ++k4) {
            float4 hv4 = ((const float4*)sh[wv])[k4];
            acc2 = fmaf(hv4.x, sWc[(k4 * 4 + 0) * HID + f], acc2);
            acc2 = fmaf(hv4.y, sWc[(k4 * 4 + 1) * HID + f], acc2);
            acc2 = fmaf(hv4.z, sWc[(k4 * 4 + 2) * HID + f], acc2);
            acc2 = fmaf(hv4.w, sWc[(k4 * 4 + 3) * HID + f], acc2);
        }
        t2b[(size_t)plane * n * 32 + (size_t)node * 32 + fin] = f2bf(acc2 * dinv[node]);
    }
}

__global__ __launch_bounds__(256) void k_bn_conv(const float* __restrict__ agg,
                                                 const float* __restrict__ stats,
                                                 const float* __restrict__ gamma,
                                                 const float* __restrict__ beta,
                                                 const float* __restrict__ W,
                                                 const float* __restrict__ b,
                                                 const float* __restrict__ dinv,
                                                 float* __restrict__ h,
                                                 unsigned short* __restrict__ t2b, int n, float invN) {
    __shared__ float sW[HID * HID];
    __shared__ float sh[4][HID];
    for (int i = threadIdx.x; i < HID * HID; i += blockDim.x) sW[i] = W[i];
    __syncthreads();
    int f = threadIdx.x & 63;
    int wv = threadIdx.x >> 6;
    int plane = f >> 5, fin = f & 31;
    float mu = stats[f] * invN;
    float var = fmaxf(stats[HID + f] * invN - mu * mu, 0.0f);
    float scale = rsqrtf(var + BN_EPS) * gamma[f];
    float shift = beta[f];
    float bf = b[f];
    int w0 = blockIdx.x * 4 + wv;
    int nw = gridDim.x * 4;
    for (int node = w0; node < n; node += nw) {
        size_t gid = (size_t)node * HID + f;
        float bnv = (agg[gid] - mu) * scale + shift;
        float hv = fmaxf(bnv, 0.0f) + h[gid];
        h[gid] = hv;
        sh[wv][f] = hv;
        float acc = bf;
#pragma unroll
        for (int k4 = 0; k4 < HID / 4; ++k4) {
            float4 hv4 = ((const float4*)sh[wv])[k4];
            acc = fmaf(hv4.x, sW[(k4 * 4 + 0) * HID + f], acc);
            acc = fmaf(hv4.y, sW[(k4 * 4 + 1) * HID + f], acc);
            acc = fmaf(hv4.z, sW[(k4 * 4 + 2) * HID + f], acc);
            acc = fmaf(hv4.w, sW[(k4 * 4 + 3) * HID + f], acc);
        }
        t2b[(size_t)plane * n * 32 + (size_t)node * 32 + fin] = f2bf(acc * dinv[node]);
    }
}

// one 4-lane group per node per plane (uint4 = 64-B plane row); blockIdx.y = plane.
// Each pass gathers from a 3.2 MB table -> fits per-XCD L2.
__global__ __launch_bounds__(256) void k_aggregate(const int* __restrict__ rowbeg,
                                                   const int* __restrict__ rowend,
                                                   const int* __restrict__ csr_src,
                                                   const unsigned short* __restrict__ t2b,
                                                   const float* __restrict__ dinv,
                                                   float* __restrict__ agg,
                                                   float* __restrict__ stats, int n) {
    __shared__ float lsum[HID], lsq[HID];
    if (threadIdx.x < HID) { lsum[threadIdx.x] = 0.0f; lsq[threadIdx.x] = 0.0f; }
    __syncthreads();

    const int plane = blockIdx.y;
    const unsigned short* tb = t2b + (size_t)plane * n * 32;

    int l4 = threadIdx.x & 3;
    int node = blockIdx.x * 64 + (threadIdx.x >> 2);

    float4 r0 = make_float4(0.f, 0.f, 0.f, 0.f);
    float4 r1 = make_float4(0.f, 0.f, 0.f, 0.f);

    if (node < n) {
        int beg = rowbeg[node], end = rowend[node];
        uint4 sv = ((const uint4*)(tb + (size_t)node * 32))[l4];
        float4 a0, a1;
        a0.x = bflo(sv.x); a0.y = bfhi(sv.x); a0.z = bflo(sv.y); a0.w = bfhi(sv.y);
        a1.x = bflo(sv.z); a1.y = bfhi(sv.z); a1.z = bflo(sv.w); a1.w = bfhi(sv.w);
        int j = beg;
        for (; j + 8 <= end; j += 8) {
            int s0 = csr_src[j + 0], s1 = csr_src[j + 1];
            int s2 = csr_src[j + 2], s3 = csr_src[j + 3];
            int s4 = csr_src[j + 4], s5 = csr_src[j + 5];
            int s6 = csr_src[j + 6], s7 = csr_src[j + 7];
            uint4 v0 = ((const uint4*)(tb + (size_t)s0 * 32))[l4];
            uint4 v1 = ((const uint4*)(tb + (size_t)s1 * 32))[l4];
            uint4 v2 = ((const uint4*)(tb + (size_t)s2 * 32))[l4];
            uint4 v3 = ((const uint4*)(tb + (size_t)s3 * 32))[l4];
            uint4 v4 = ((const uint4*)(tb + (size_t)s4 * 32))[l4];
            uint4 v5 = ((const uint4*)(tb + (size_t)s5 * 32))[l4];
            uint4 v6 = ((const uint4*)(tb + (size_t)s6 * 32))[l4];
            uint4 v7 = ((const uint4*)(tb + (size_t)s7 * 32))[l4];
            a0.x += bflo(v0.x) + bflo(v1.x) + bflo(v2.x) + bflo(v3.x)
                  + bflo(v4.x) + bflo(v5.x) + bflo(v6.x) + bflo(v7.x);
            a0.y += bfhi(v0.x) + bfhi(v1.x) + bfhi(v2.x) + bfhi(v3.x)
                  + bfhi(v4.x) + bfhi(v5.x) + bfhi(v6.x) + bfhi(v7.x);
            a0.z += bflo(v0.y) + bflo(v1.y) + bflo(v2.y) + bflo(v3.y)
                  + bflo(v4.y) + bflo(v5.y) + bflo(v6.y) + bflo(v7.y);
            a0.w += bfhi(v0.y) + bfhi(v1.y) + bfhi(v2.y) + bfhi(v3.y)
                  + bfhi(v4.y) + bfhi(v5.y) + bfhi(v6.y) + bfhi(v7.y);
            a1.x += bflo(v0.z) + bflo(v1.z) + bflo(v2.z) + bflo(v3.z)
                  + bflo(v4.z) + bflo(v5.z) + bflo(v6.z) + bflo(v7.z);
            a1.y += bfhi(v0.z) + bfhi(v1.z) + bfhi(v2.z) + bfhi(v3.z)
                  + bfhi(v4.z) + bfhi(v5.z) + bfhi(v6.z) + bfhi(v7.z);
            a1.z += bflo(v0.w) + bflo(v1.w) + bflo(v2.w) + bflo(v3.w)
                  + bflo(v4.w) + bflo(v5.w) + bflo(v6.w) + bflo(v7.w);
            a1.w += bfhi(v0.w) + bfhi(v1.w) + bfhi(v2.w) + bfhi(v3.w)
                  + bfhi(v4.w) + bfhi(v5.w) + bfhi(v6.w) + bfhi(v7.w);
        }
        for (; j < end; ++j) {
            int s = csr_src[j];
            uint4 v = ((const uint4*)(tb + (size_t)s * 32))[l4];
            a0.x += bflo(v.x); a0.y += bfhi(v.x); a0.z += bflo(v.y); a0.w += bfhi(v.y);
            a1.x += bflo(v.z); a1.y += bfhi(v.z); a1.z += bflo(v.w); a1.w += bfhi(v.w);
        }
        float dv = dinv[node];
        r0.x = a0.x * dv; r0.y = a0.y * dv; r0.z = a0.z * dv; r0.w = a0.w * dv;
        r1.x = a1.x * dv; r1.y = a1.y * dv; r1.z = a1.z * dv; r1.w = a1.w * dv;
        float4* ar = (float4*)(agg + (size_t)node * HID + plane * 32);
        ar[l4 * 2 + 0] = r0;
        ar[l4 * 2 + 1] = r1;
    }

    // BN stats for this plane's 32 features
    float4 q0, q1;
    q0.x = r0.x * r0.x; q0.y = r0.y * r0.y; q0.z = r0.z * r0.z; q0.w = r0.w * r0.w;
    q1.x = r1.x * r1.x; q1.y = r1.y * r1.y; q1.z = r1.z * r1.z; q1.w = r1.w * r1.w;
#pragma unroll
    for (int off = 4; off < 64; off <<= 1) {
        r0.x += __shfl_xor(r0.x, off, 64); q0.x += __shfl_xor(q0.x, off, 64);
        r0.y += __shfl_xor(r0.y, off, 64); q0.y += __shfl_xor(q0.y, off, 64);
        r0.z += __shfl_xor(r0.z, off, 64); q0.z += __shfl_xor(q0.z, off, 64);
        r0.w += __shfl_xor(r0.w, off, 64); q0.w += __shfl_xor(q0.w, off, 64);
        r1.x += __shfl_xor(r1.x, off, 64); q1.x += __shfl_xor(q1.x, off, 64);
        r1.y += __shfl_xor(r1.y, off, 64); q1.y += __shfl_xor(q1.y, off, 64);
        r1.z += __shfl_xor(r1.z, off, 64); q1.z += __shfl_xor(q1.z, off, 64);
        r1.w += __shfl_xor(r1.w, off, 64); q1.w += __shfl_xor(q1.w, off, 64);
    }
    if ((threadIdx.x & 63) < 4) {
        int f0 = plane * 32 + l4 * 8;
        atomicAdd(&lsum[f0 + 0], r0.x); atomicAdd(&lsq[f0 + 0], q0.x);
        atomicAdd(&lsum[f0 + 1], r0.y); atomicAdd(&lsq[f0 + 1], q0.y);
        atomicAdd(&lsum[f0 + 2], r0.z); atomicAdd(&lsq[f0 + 2], q0.z);
        atomicAdd(&lsum[f0 + 3], r0.w); atomicAdd(&lsq[f0 + 3], q0.w);
        atomicAdd(&lsum[f0 + 4], r1.x); atomicAdd(&lsq[f0 + 4], q1.x);
        atomicAdd(&lsum[f0 + 5], r1.y); atomicAdd(&lsq[f0 + 5], q1.y);
        atomicAdd(&lsum[f0 + 6], r1.z); atomicAdd(&lsq[f0 + 6], q1.z);
        atomicAdd(&lsum[f0 + 7], r1.w); atomicAdd(&lsq[f0 + 7], q1.w);
    }
    __syncthreads();
    int fs = plane * 32 + (threadIdx.x & 31);
    if (threadIdx.x < 32) {
        atomicAdd(&stats[fs], lsum[fs]);
        atomicAdd(&stats[HID + fs], lsq[fs]);
    }
}

// final: h = relu(bn(agg)) + h
__global__ __launch_bounds__(256) void k_bn_apply(const float* __restrict__ agg,
                                                  const float* __restrict__ stats,
                                                  const float* __restrict__ gamma,
                                                  const float* __restrict__ beta,
                                                  float* __restrict__ h, int n, float invN) {
    int gid = blockIdx.x * blockDim.x + threadIdx.x;
    int node = gid >> 6, f = gid & 63;
    if (node >= n) return;
    float mu = stats[f] * invN;
    float var = fmaxf(stats[HID + f] * invN - mu * mu, 0.0f);
    float bn = (agg[gid] - mu) * rsqrtf(var + BN_EPS) * gamma[f] + beta[f];
    h[gid] = fmaxf(bn, 0.0f) + h[gid];
}

extern "C" void kernel_launch(void* const* d_in, const int* in_sizes, int n_in,
                              void* d_out, int out_size, void* d_ws, size_t ws_size,
                              hipStream_t stream) {
    const float* x       = (const float*)d_in[0];
    const int*   ei      = (const int*)d_in[1];
    const float* W_embed = (const float*)d_in[2];
    const float* b_embed = (const float*)d_in[3];
    const float* W_convs = (const float*)d_in[4];
    const float* b_convs = (const float*)d_in[5];
    const float* gamma   = (const float*)d_in[6];
    const float* beta    = (const float*)d_in[7];
    float* h = (float*)d_out;

    const int n = in_sizes[0] / IN_F;   // 50000
    const int e = in_sizes[1] / 2;      // 800000
    const int* src = ei;
    const int* dst = ei + e;

    unsigned short* t2b = (unsigned short*)d_ws;            // 2 planes * n*32 bf16
    float* agg      = (float*)(t2b + (size_t)n * HID);      // n*HID f32
    float* dinv     = agg + (size_t)n * HID;                // n
    float* statsAll = dinv + n;                             // 3*128
    int*   rowbeg   = (int*)(statsAll + 2 * HID * N_LAYERS);
    int*   fillcur  = rowbeg + n;
    int*   csr_src  = fillcur + n;
    int*   cursor   = csr_src + e;

    const int nodeBlocks  = (n + 255) / 256;
    const int nfBlocks    = (n * HID + 255) / 256;
    const int edgeBlocks  = (e + 255) / 256;
    const dim3 aggGrid((n + 63) / 64, 2);   // one 4-lane group per node, 2 planes
    const int embedBlocks = 1536;
    const int convBlocks  = 2048;

    k_zero<<<nodeBlocks, 256, 0, stream>>>(fillcur, cursor, statsAll, n);
    k_hist<<<edgeBlocks, 256, 0, stream>>>(dst, fillcur, e);
    k_assign<<<nodeBlocks, 256, 0, stream>>>(fillcur, rowbeg, dinv, cursor, n);
    k_fill<<<edgeBlocks, 256, 0, stream>>>(src, dst, fillcur, csr_src, e);

    const float invN = 1.0f / (float)n;

    k_embed_conv<<<embedBlocks, 256, 0, stream>>>(x, W_embed, b_embed, W_convs, b_convs,
                                                  dinv, h, t2b, n);

    for (int l = 0; l < N_LAYERS; ++l) {
        float* stats = statsAll + (size_t)l * 2 * HID;
        k_aggregate<<<aggGrid, 256, 0, stream>>>(rowbeg, fillcur, csr_src, t2b, dinv,
                                                 agg, stats, n);
        if (l < N_LAYERS - 1) {
            const float* Wl = W_convs + (size_t)(l + 1) * HID * HID;
            const float* bl = b_convs + (size_t)(l + 1) * HID;
            k_bn_conv<<<convBlocks, 256, 0, stream>>>(agg, stats, gamma, beta, Wl, bl, dinv,
                                                      h, t2b, n, invN);
        } else {
            k_bn_apply<<<nfBlocks, 256, 0, stream>>>(agg, stats, gamma, beta, h, n, invN);
        }
    }
}

// Round 8
// 270.905 us; speedup vs baseline: 3.0724x; 1.0948x over previous
//
#include <hip/hip_runtime.h>

#define IN_F 32
#define HID 64
#define N_LAYERS 3
#define BN_EPS 1e-5f

__device__ __forceinline__ unsigned short f2bf(float x) {
    unsigned u = __float_as_uint(x);
    u += 0x7fffu + ((u >> 16) & 1u);
    return (unsigned short)(u >> 16);
}
__device__ __forceinline__ float bflo(unsigned v) { return __uint_as_float(v << 16); }
__device__ __forceinline__ float bfhi(unsigned v) { return __uint_as_float(v & 0xffff0000u); }

// ---------------- CSR build ----------------
__global__ __launch_bounds__(256) void k_zero(int* cnt, int* cursor, float* statsAll, int n) {
    int i = blockIdx.x * blockDim.x + threadIdx.x;
    if (i < n) cnt[i] = 0;
    if (i == 0) *cursor = 0;
    if (i < 2 * HID * N_LAYERS) statsAll[i] = 0.0f;
}

// hist + within-segment rank in one pass (rank = atomic return value)
__global__ __launch_bounds__(256) void k_hist_rank(const int* __restrict__ dst, int* cnt,
                                                   unsigned short* __restrict__ rank, int e) {
    int i = blockIdx.x * blockDim.x + threadIdx.x;
    if (i >= e) return;
    int r = atomicAdd(&cnt[dst[i]], 1);
    rank[i] = (unsigned short)r;
}

// segment begin via intra-wave exclusive scan + ONE cursor atomic per wave
__global__ __launch_bounds__(256) void k_assign(const int* __restrict__ cnt, int* rowbeg,
                                                float* dinv, int* cursor, int n) {
    int i = blockIdx.x * blockDim.x + threadIdx.x;
    int lane = threadIdx.x & 63;
    int c = (i < n) ? cnt[i] : 0;
    int s = c;
#pragma unroll
    for (int off = 1; off < 64; off <<= 1) {
        int t = __shfl_up(s, off, 64);
        if (lane >= off) s += t;
    }
    int total = __shfl(s, 63, 64);
    int base = 0;
    if (lane == 63) base = atomicAdd(cursor, total);
    base = __shfl(base, 63, 64);
    if (i < n) {
        rowbeg[i] = base + s - c;
        dinv[i] = rsqrtf((float)(c + 1));
    }
}

// atomic-free fill: pos = rowbeg[dst] + rank
__global__ __launch_bounds__(256) void k_fill(const int* __restrict__ src,
                                              const int* __restrict__ dst,
                                              const int* __restrict__ rowbeg,
                                              const unsigned short* __restrict__ rank,
                                              unsigned short* __restrict__ csr_src, int e) {
    int i = blockIdx.x * blockDim.x + threadIdx.x;
    if (i >= e) return;
    int pos = rowbeg[dst[i]] + (int)rank[i];
    csr_src[pos] = (unsigned short)src[i];
}

// ---------------- fused dense ops (weight-stationary, grid-stride) ----------------
// planar t2b: plane p (p=0,1) holds features p*32..p*32+31, 32 bf16 (64 B) per node.
__global__ __launch_bounds__(256) void k_embed_conv(const float* __restrict__ x,
                                                    const float* __restrict__ We,
                                                    const float* __restrict__ be,
                                                    const float* __restrict__ Wc,
                                                    const float* __restrict__ bc,
                                                    const float* __restrict__ dinv,
                                                    float* __restrict__ h,
                                                    unsigned short* __restrict__ t2b, int n) {
    __shared__ float sWe[IN_F * HID];
    __shared__ float sWc[HID * HID];
    __shared__ float sh[4][HID];
    for (int i = threadIdx.x; i < IN_F * HID; i += blockDim.x) sWe[i] = We[i];
    for (int i = threadIdx.x; i < HID * HID; i += blockDim.x) sWc[i] = Wc[i];
    __syncthreads();
    int f = threadIdx.x & 63;
    int wv = threadIdx.x >> 6;
    int plane = f >> 5, fin = f & 31;
    float bef = be[f], bcf = bc[f];
    int w0 = blockIdx.x * 4 + wv;
    int nw = gridDim.x * 4;
    for (int node = w0; node < n; node += nw) {
        const float* xr = x + (size_t)node * IN_F;
        float acc = bef;
#pragma unroll
        for (int k = 0; k < IN_F; ++k) acc = fmaf(xr[k], sWe[k * HID + f], acc);
        float hv = fmaxf(acc, 0.0f);
        h[(size_t)node * HID + f] = hv;
        sh[wv][f] = hv;
        float acc2 = bcf;
#pragma unroll
        for (int k4 = 0; k4 < HID / 4; ++k4) {
            float4 hv4 = ((const float4*)sh[wv])[k4];
            acc2 = fmaf(hv4.x, sWc[(k4 * 4 + 0) * HID + f], acc2);
            acc2 = fmaf(hv4.y, sWc[(k4 * 4 + 1) * HID + f], acc2);
            acc2 = fmaf(hv4.z, sWc[(k4 * 4 + 2) * HID + f], acc2);
            acc2 = fmaf(hv4.w, sWc[(k4 * 4 + 3) * HID + f], acc2);
        }
        t2b[(size_t)plane * n * 32 + (size_t)node * 32 + fin] = f2bf(acc2 * dinv[node]);
    }
}

__global__ __launch_bounds__(256) void k_bn_conv(const float* __restrict__ agg,
                                                 const float* __restrict__ stats,
                                                 const float* __restrict__ gamma,
                                                 const float* __restrict__ beta,
                                                 const float* __restrict__ W,
                                                 const float* __restrict__ b,
                                                 const float* __restrict__ dinv,
                                                 float* __restrict__ h,
                                                 unsigned short* __restrict__ t2b, int n, float invN) {
    __shared__ float sW[HID * HID];
    __shared__ float sh[4][HID];
    for (int i = threadIdx.x; i < HID * HID; i += blockDim.x) sW[i] = W[i];
    __syncthreads();
    int f = threadIdx.x & 63;
    int wv = threadIdx.x >> 6;
    int plane = f >> 5, fin = f & 31;
    float mu = stats[f] * invN;
    float var = fmaxf(stats[HID + f] * invN - mu * mu, 0.0f);
    float scale = rsqrtf(var + BN_EPS) * gamma[f];
    float shift = beta[f];
    float bf = b[f];
    int w0 = blockIdx.x * 4 + wv;
    int nw = gridDim.x * 4;
    for (int node = w0; node < n; node += nw) {
        size_t gid = (size_t)node * HID + f;
        float bnv = (agg[gid] - mu) * scale + shift;
        float hv = fmaxf(bnv, 0.0f) + h[gid];
        h[gid] = hv;
        sh[wv][f] = hv;
        float acc = bf;
#pragma unroll
        for (int k4 = 0; k4 < HID / 4; ++k4) {
            float4 hv4 = ((const float4*)sh[wv])[k4];
            acc = fmaf(hv4.x, sW[(k4 * 4 + 0) * HID + f], acc);
            acc = fmaf(hv4.y, sW[(k4 * 4 + 1) * HID + f], acc);
            acc = fmaf(hv4.z, sW[(k4 * 4 + 2) * HID + f], acc);
            acc = fmaf(hv4.w, sW[(k4 * 4 + 3) * HID + f], acc);
        }
        t2b[(size_t)plane * n * 32 + (size_t)node * 32 + fin] = f2bf(acc * dinv[node]);
    }
}

// one 4-lane group per node per plane (uint4 = 64-B plane row); blockIdx.y = plane.
__global__ __launch_bounds__(256) void k_aggregate(const int* __restrict__ rowbeg,
                                                   const int* __restrict__ cnt,
                                                   const unsigned short* __restrict__ csr_src,
                                                   const unsigned short* __restrict__ t2b,
                                                   const float* __restrict__ dinv,
                                                   float* __restrict__ agg,
                                                   float* __restrict__ stats, int n) {
    __shared__ float lsum[HID], lsq[HID];
    if (threadIdx.x < HID) { lsum[threadIdx.x] = 0.0f; lsq[threadIdx.x] = 0.0f; }
    __syncthreads();

    const int plane = blockIdx.y;
    const unsigned short* tb = t2b + (size_t)plane * n * 32;

    int l4 = threadIdx.x & 3;
    int node = blockIdx.x * 64 + (threadIdx.x >> 2);

    float4 r0 = make_float4(0.f, 0.f, 0.f, 0.f);
    float4 r1 = make_float4(0.f, 0.f, 0.f, 0.f);

    if (node < n) {
        int beg = rowbeg[node], end = beg + cnt[node];
        uint4 sv = ((const uint4*)(tb + (size_t)node * 32))[l4];
        float4 a0, a1;
        a0.x = bflo(sv.x); a0.y = bfhi(sv.x); a0.z = bflo(sv.y); a0.w = bfhi(sv.y);
        a1.x = bflo(sv.z); a1.y = bfhi(sv.z); a1.z = bflo(sv.w); a1.w = bfhi(sv.w);
        int j = beg;
        for (; j + 8 <= end; j += 8) {
            int s0 = csr_src[j + 0], s1 = csr_src[j + 1];
            int s2 = csr_src[j + 2], s3 = csr_src[j + 3];
            int s4 = csr_src[j + 4], s5 = csr_src[j + 5];
            int s6 = csr_src[j + 6], s7 = csr_src[j + 7];
            uint4 v0 = ((const uint4*)(tb + (size_t)s0 * 32))[l4];
            uint4 v1 = ((const uint4*)(tb + (size_t)s1 * 32))[l4];
            uint4 v2 = ((const uint4*)(tb + (size_t)s2 * 32))[l4];
            uint4 v3 = ((const uint4*)(tb + (size_t)s3 * 32))[l4];
            uint4 v4 = ((const uint4*)(tb + (size_t)s4 * 32))[l4];
            uint4 v5 = ((const uint4*)(tb + (size_t)s5 * 32))[l4];
            uint4 v6 = ((const uint4*)(tb + (size_t)s6 * 32))[l4];
            uint4 v7 = ((const uint4*)(tb + (size_t)s7 * 32))[l4];
            a0.x += bflo(v0.x) + bflo(v1.x) + bflo(v2.x) + bflo(v3.x)
                  + bflo(v4.x) + bflo(v5.x) + bflo(v6.x) + bflo(v7.x);
            a0.y += bfhi(v0.x) + bfhi(v1.x) + bfhi(v2.x) + bfhi(v3.x)
                  + bfhi(v4.x) + bfhi(v5.x) + bfhi(v6.x) + bfhi(v7.x);
            a0.z += bflo(v0.y) + bflo(v1.y) + bflo(v2.y) + bflo(v3.y)
                  + bflo(v4.y) + bflo(v5.y) + bflo(v6.y) + bflo(v7.y);
            a0.w += bfhi(v0.y) + bfhi(v1.y) + bfhi(v2.y) + bfhi(v3.y)
                  + bfhi(v4.y) + bfhi(v5.y) + bfhi(v6.y) + bfhi(v7.y);
            a1.x += bflo(v0.z) + bflo(v1.z) + bflo(v2.z) + bflo(v3.z)
                  + bflo(v4.z) + bflo(v5.z) + bflo(v6.z) + bflo(v7.z);
            a1.y += bfhi(v0.z) + bfhi(v1.z) + bfhi(v2.z) + bfhi(v3.z)
                  + bfhi(v4.z) + bfhi(v5.z) + bfhi(v6.z) + bfhi(v7.z);
            a1.z += bflo(v0.w) + bflo(v1.w) + bflo(v2.w) + bflo(v3.w)
                  + bflo(v4.w) + bflo(v5.w) + bflo(v6.w) + bflo(v7.w);
            a1.w += bfhi(v0.w) + bfhi(v1.w) + bfhi(v2.w) + bfhi(v3.w)
                  + bfhi(v4.w) + bfhi(v5.w) + bfhi(v6.w) + bfhi(v7.w);
        }
        for (; j < end; ++j) {
            int s = csr_src[j];
            uint4 v = ((const uint4*)(tb + (size_t)s * 32))[l4];
            a0.x += bflo(v.x); a0.y += bfhi(v.x); a0.z += bflo(v.y); a0.w += bfhi(v.y);
            a1.x += bflo(v.z); a1.y += bfhi(v.z); a1.z += bflo(v.w); a1.w += bfhi(v.w);
        }
        float dv = dinv[node];
        r0.x = a0.x * dv; r0.y = a0.y * dv; r0.z = a0.z * dv; r0.w = a0.w * dv;
        r1.x = a1.x * dv; r1.y = a1.y * dv; r1.z = a1.z * dv; r1.w = a1.w * dv;
        float4* ar = (float4*)(agg + (size_t)node * HID + plane * 32);
        ar[l4 * 2 + 0] = r0;
        ar[l4 * 2 + 1] = r1;
    }

    float4 q0, q1;
    q0.x = r0.x * r0.x; q0.y = r0.y * r0.y; q0.z = r0.z * r0.z; q0.w = r0.w * r0.w;
    q1.x = r1.x * r1.x; q1.y = r1.y * r1.y; q1.z = r1.z * r1.z; q1.w = r1.w * r1.w;
#pragma unroll
    for (int off = 4; off < 64; off <<= 1) {
        r0.x += __shfl_xor(r0.x, off, 64); q0.x += __shfl_xor(q0.x, off, 64);
        r0.y += __shfl_xor(r0.y, off, 64); q0.y += __shfl_xor(q0.y, off, 64);
        r0.z += __shfl_xor(r0.z, off, 64); q0.z += __shfl_xor(q0.z, off, 64);
        r0.w += __shfl_xor(r0.w, off, 64); q0.w += __shfl_xor(q0.w, off, 64);
        r1.x += __shfl_xor(r1.x, off, 64); q1.x += __shfl_xor(q1.x, off, 64);
        r1.y += __shfl_xor(r1.y, off, 64); q1.y += __shfl_xor(q1.y, off, 64);
        r1.z += __shfl_xor(r1.z, off, 64); q1.z += __shfl_xor(q1.z, off, 64);
        r1.w += __shfl_xor(r1.w, off, 64); q1.w += __shfl_xor(q1.w, off, 64);
    }
    if ((threadIdx.x & 63) < 4) {
        int f0 = plane * 32 + l4 * 8;
        atomicAdd(&lsum[f0 + 0], r0.x); atomicAdd(&lsq[f0 + 0], q0.x);
        atomicAdd(&lsum[f0 + 1], r0.y); atomicAdd(&lsq[f0 + 1], q0.y);
        atomicAdd(&lsum[f0 + 2], r0.z); atomicAdd(&lsq[f0 + 2], q0.z);
        atomicAdd(&lsum[f0 + 3], r0.w); atomicAdd(&lsq[f0 + 3], q0.w);
        atomicAdd(&lsum[f0 + 4], r1.x); atomicAdd(&lsq[f0 + 4], q1.x);
        atomicAdd(&lsum[f0 + 5], r1.y); atomicAdd(&lsq[f0 + 5], q1.y);
        atomicAdd(&lsum[f0 + 6], r1.z); atomicAdd(&lsq[f0 + 6], q1.z);
        atomicAdd(&lsum[f0 + 7], r1.w); atomicAdd(&lsq[f0 + 7], q1.w);
    }
    __syncthreads();
    int fs = plane * 32 + (threadIdx.x & 31);
    if (threadIdx.x < 32) {
        atomicAdd(&stats[fs], lsum[fs]);
        atomicAdd(&stats[HID + fs], lsq[fs]);
    }
}

// final: h = relu(bn(agg)) + h
__global__ __launch_bounds__(256) void k_bn_apply(const float* __restrict__ agg,
                                                  const float* __restrict__ stats,
                                                  const float* __restrict__ gamma,
                                                  const float* __restrict__ beta,
                                                  float* __restrict__ h, int n, float invN) {
    int gid = blockIdx.x * blockDim.x + threadIdx.x;
    int node = gid >> 6, f = gid & 63;
    if (node >= n) return;
    float mu = stats[f] * invN;
    float var = fmaxf(stats[HID + f] * invN - mu * mu, 0.0f);
    float bn = (agg[gid] - mu) * rsqrtf(var + BN_EPS) * gamma[f] + beta[f];
    h[gid] = fmaxf(bn, 0.0f) + h[gid];
}

extern "C" void kernel_launch(void* const* d_in, const int* in_sizes, int n_in,
                              void* d_out, int out_size, void* d_ws, size_t ws_size,
                              hipStream_t stream) {
    const float* x       = (const float*)d_in[0];
    const int*   ei      = (const int*)d_in[1];
    const float* W_embed = (const float*)d_in[2];
    const float* b_embed = (const float*)d_in[3];
    const float* W_convs = (const float*)d_in[4];
    const float* b_convs = (const float*)d_in[5];
    const float* gamma   = (const float*)d_in[6];
    const float* beta    = (const float*)d_in[7];
    float* h = (float*)d_out;

    const int n = in_sizes[0] / IN_F;   // 50000
    const int e = in_sizes[1] / 2;      // 800000
    const int* src = ei;
    const int* dst = ei + e;

    unsigned short* t2b = (unsigned short*)d_ws;            // 2 planes * n*32 bf16
    float* agg      = (float*)(t2b + (size_t)n * HID);      // n*HID f32
    float* dinv     = agg + (size_t)n * HID;                // n
    float* statsAll = dinv + n;                             // 3*128
    int*   rowbeg   = (int*)(statsAll + 2 * HID * N_LAYERS);// n
    int*   cnt      = rowbeg + n;                           // n
    int*   cursor   = cnt + n;                              // 1
    unsigned short* csr_src = (unsigned short*)(cursor + 1);// e
    unsigned short* rank    = csr_src + e;                  // e

    const int nodeBlocks  = (n + 255) / 256;
    const int nfBlocks    = (n * HID + 255) / 256;
    const int edgeBlocks  = (e + 255) / 256;
    const dim3 aggGrid((n + 63) / 64, 2);
    const int embedBlocks = 1536;
    const int convBlocks  = 2048;

    k_zero<<<nodeBlocks, 256, 0, stream>>>(cnt, cursor, statsAll, n);
    k_hist_rank<<<edgeBlocks, 256, 0, stream>>>(dst, cnt, rank, e);
    k_assign<<<nodeBlocks, 256, 0, stream>>>(cnt, rowbeg, dinv, cursor, n);
    k_fill<<<edgeBlocks, 256, 0, stream>>>(src, dst, rowbeg, rank, csr_src, e);

    const float invN = 1.0f / (float)n;

    k_embed_conv<<<embedBlocks, 256, 0, stream>>>(x, W_embed, b_embed, W_convs, b_convs,
                                                  dinv, h, t2b, n);

    for (int l = 0; l < N_LAYERS; ++l) {
        float* stats = statsAll + (size_t)l * 2 * HID;
        k_aggregate<<<aggGrid, 256, 0, stream>>>(rowbeg, cnt, csr_src, t2b, dinv,
                                                 agg, stats, n);
        if (l < N_LAYERS - 1) {
            const float* Wl = W_convs + (size_t)(l + 1) * HID * HID;
            const float* bl = b_convs + (size_t)(l + 1) * HID;
            k_bn_conv<<<convBlocks, 256, 0, stream>>>(agg, stats, gamma, beta, Wl, bl, dinv,
                                                      h, t2b, n, invN);
        } else {
            k_bn_apply<<<nfBlocks, 256, 0, stream>>>(agg, stats, gamma, beta, h, n, invN);
        }
    }
}